// Round 1
// baseline (348.408 us; speedup 1.0000x reference)
//
#include <hip/hip_runtime.h>

#define N_PRED 25200
#define CONF 0.25f
#define IOU_THR 0.45f
#define MAXD 300
#define IMGW 640
#define CROPW 64
#define HISTN 16640

typedef float f32x4 __attribute__((ext_vector_type(4)));
typedef short s16x8 __attribute__((ext_vector_type(8)));
typedef unsigned long long u64;

// ---- workspace layout (bytes). Total required: 58,473,216 (~55.8 MB) ----
#define OFF_HIST   0u            // 16640*4 = 66560
#define OFF_CNT    66560u        // counters (cnt at +0, cut at +64)
#define OFF_CUT    66624u
#define OFF_CAND   66816u        // 1024 * 8 = 8192
#define CTRL_BYTES 75008u        // memset [0, CTRL_BYTES) each call
#define OFF_BOXES  75008u        // 300*4*4
#define OFF_XY1    79872u        // 300*2*4
#define OFF_VALID  82432u        // 300*4
#define OFF_KEEP   83712u        // 300*4
#define OFF_SUP    84992u        // 300*5*8
#define OFF_H      97024u        // 8*300*128*4 = 1228800
#define OFF_FEATS  1325824u      // 320*16384*2 = 10485760
#define OFF_W1T    11811584u     // 8*128*16384*2 = 33554432
#define OFF_PART   45366016u     // 8*8*320*128*4 = 13107200

__device__ inline unsigned short f2bf(float x) {
  unsigned u = __float_as_uint(x);
  u += 0x7FFFu + ((u >> 16) & 1u);   // round-to-nearest-even
  return (unsigned short)(u >> 16);
}

// ---------------- stage 1: score histogram (radix cut for top-300) -------
__global__ __launch_bounds__(256) void k_hist(const float* __restrict__ preds,
                                              unsigned* __restrict__ hist) {
  int i = blockIdx.x * 256 + threadIdx.x;
  if (i >= N_PRED) return;
  float s = preds[i * 6 + 4] * preds[i * 6 + 5];
  if (s > CONF) atomicAdd(&hist[__float_as_uint(s) >> 16], 1u);
}

// find largest bucket b with suffix-count(b) >= 300
__global__ __launch_bounds__(256) void k_findcut(const unsigned* __restrict__ hist,
                                                 unsigned* __restrict__ cut) {
  __shared__ unsigned s[256];
  __shared__ unsigned carry, res;
  __shared__ int found;
  int t = threadIdx.x;
  if (t == 0) { carry = 0u; res = 0u; found = 0; }
  __syncthreads();
  for (int base = HISTN - 256; base >= 0; base -= 256) {
    s[t] = hist[base + t];
    __syncthreads();
    for (int off = 1; off < 256; off <<= 1) {          // right-inclusive scan
      unsigned add = (t + off < 256) ? s[t + off] : 0u;
      __syncthreads();
      s[t] += add;
      __syncthreads();
    }
    if (carry + s[t] >= (unsigned)MAXD) atomicMax(&res, (unsigned)(base + t));
    __syncthreads();
    if (t == 0) {
      if (carry + s[0] >= (unsigned)MAXD) found = 1;
      else carry += s[0];
    }
    __syncthreads();
    if (found) break;
  }
  if (t == 0) cut[0] = found ? res : 0u;
}

__global__ __launch_bounds__(256) void k_compact(const float* __restrict__ preds,
                                                 const unsigned* __restrict__ cut,
                                                 unsigned* __restrict__ cnt,
                                                 u64* __restrict__ cand) {
  int i = blockIdx.x * 256 + threadIdx.x;
  if (i >= N_PRED) return;
  float s = preds[i * 6 + 4] * preds[i * 6 + 5];
  if (s <= CONF) return;
  unsigned bits = __float_as_uint(s);
  if ((bits >> 16) < cut[0]) return;
  unsigned pos = atomicAdd(cnt, 1u);
  if (pos < 1024u)
    cand[pos] = ((u64)bits << 32) | (u64)(0xFFFFFFFFu - (unsigned)i);  // ties: lower idx first
}

// bitonic sort 1024 u64 descending; emit boxes / crop coords / valid flags
__global__ __launch_bounds__(1024) void k_sortprep(const float* __restrict__ preds,
                                                   const u64* __restrict__ cand,
                                                   float* __restrict__ boxes,
                                                   int* __restrict__ xy1,
                                                   float* __restrict__ validf) {
  __shared__ u64 sk[1024];
  int t = threadIdx.x;
  sk[t] = cand[t];
  __syncthreads();
  for (int k = 2; k <= 1024; k <<= 1)
    for (int j = k >> 1; j > 0; j >>= 1) {
      int p = t ^ j;
      if (p > t) {
        u64 a = sk[t], b = sk[p];
        bool up = ((t & k) == 0);
        bool sw = up ? (a < b) : (a > b);      // descending overall
        if (sw) { sk[t] = b; sk[p] = a; }
      }
      __syncthreads();
    }
  if (t < MAXD) {
    u64 key = sk[t];
    if (key != 0ull) {
      int idx = (int)(0xFFFFFFFFu - (unsigned)(key & 0xFFFFFFFFull));
      float cx = preds[idx * 6 + 0], cy = preds[idx * 6 + 1];
      float w  = preds[idx * 6 + 2], h  = preds[idx * 6 + 3];
      float x1 = cx - w * 0.5f, y1 = cy - h * 0.5f;
      float x2 = cx + w * 0.5f, y2 = cy + h * 0.5f;
      boxes[t * 4 + 0] = x1; boxes[t * 4 + 1] = y1;
      boxes[t * 4 + 2] = x2; boxes[t * 4 + 3] = y2;
      int xi = (int)rintf(x1); xi = min(max(xi, 0), IMGW - CROPW);
      int yi = (int)rintf(y1); yi = min(max(yi, 0), IMGW - CROPW);
      xy1[t * 2 + 0] = xi; xy1[t * 2 + 1] = yi;
      validf[t] = 1.0f;
    } else {
      boxes[t * 4 + 0] = 0.f; boxes[t * 4 + 1] = 0.f;
      boxes[t * 4 + 2] = 0.f; boxes[t * 4 + 3] = 0.f;
      xy1[t * 2 + 0] = 0; xy1[t * 2 + 1] = 0;
      validf[t] = 0.f;
    }
  }
}

// supmask[i][w] : bit j of word w set iff IoU(i, j) > thr
__global__ __launch_bounds__(64) void k_iou(const float* __restrict__ boxes,
                                            u64* __restrict__ sup) {
  int i = blockIdx.x, lane = threadIdx.x;
  float x1 = boxes[i * 4 + 0], y1 = boxes[i * 4 + 1];
  float x2 = boxes[i * 4 + 2], y2 = boxes[i * 4 + 3];
  float ar = (x2 - x1) * (y2 - y1);
  for (int it = 0; it < 5; it++) {
    int j = it * 64 + lane;
    bool pred = false;
    if (j < MAXD) {
      float bx1 = boxes[j * 4 + 0], by1 = boxes[j * 4 + 1];
      float bx2 = boxes[j * 4 + 2], by2 = boxes[j * 4 + 3];
      float arj = (bx2 - bx1) * (by2 - by1);
      float iw = fmaxf(fminf(x2, bx2) - fmaxf(x1, bx1), 0.f);
      float ih = fmaxf(fminf(y2, by2) - fmaxf(y1, by1), 0.f);
      float inter = iw * ih;
      float iou = inter / (ar + arj - inter + 1e-7f);
      pred = iou > IOU_THR;
    }
    u64 bm = __ballot(pred);
    if (lane == 0) sup[i * 5 + it] = bm;
  }
}

// sequential greedy NMS on bitmasks
__global__ __launch_bounds__(64) void k_nms(const u64* __restrict__ sup,
                                            const float* __restrict__ validf,
                                            float* __restrict__ keepf) {
  __shared__ u64 skw[5];
  if (threadIdx.x == 0) {
    u64 kw[5] = {0, 0, 0, 0, 0};
    for (int j = 0; j < MAXD; j++)
      if (validf[j] > 0.5f) kw[j >> 6] |= (1ull << (j & 63));
    for (int i = 0; i < MAXD; i++) {
      int wh = i >> 6;
      u64 s = 0;
      for (int w = 0; w < wh; w++) s |= sup[i * 5 + w] & kw[w];
      s |= sup[i * 5 + wh] & kw[wh] & ((1ull << (i & 63)) - 1ull);
      if (s) kw[wh] &= ~(1ull << (i & 63));
    }
    for (int w = 0; w < 5; w++) skw[w] = kw[w];
  }
  __syncthreads();
  for (int j = threadIdx.x; j < MAXD; j += 64)
    keepf[j] = ((skw[j >> 6] >> (j & 63)) & 1ull) ? 1.f : 0.f;
}

// crop + 3x3 SAME conv(16) + ReLU + 2x2 maxpool -> feats[det][16384] (bf16)
__global__ __launch_bounds__(512) void k_cropconv(const float* __restrict__ image,
                                                  const float* __restrict__ Wc,
                                                  const float* __restrict__ bc,
                                                  const int* __restrict__ xy1,
                                                  short* __restrict__ feats) {
  int det = blockIdx.x, tid = threadIdx.x;
  if (det >= MAXD) {                       // pad rows 300..319 -> zeros
    for (int i = tid; i < 16384; i += 512) feats[(size_t)det * 16384 + i] = 0;
    return;
  }
  __shared__ float crop[3][66][68];        // zero-padded crop
  __shared__ float swg[432];
  for (int i = tid; i < 3 * 66 * 68; i += 512) ((float*)crop)[i] = 0.f;
  for (int i = tid; i < 432; i += 512) swg[i] = Wc[i];
  __syncthreads();
  int x0 = xy1[det * 2 + 0], y0 = xy1[det * 2 + 1];
  for (int i = tid; i < 3 * 64 * 64; i += 512) {
    int c = i >> 12, rem = i & 4095, y = rem >> 6, x = rem & 63;
    crop[c][y + 1][x + 1] = image[(size_t)c * (IMGW * IMGW) + (y0 + y) * IMGW + (x0 + x)];
  }
  __syncthreads();
  int ch = tid >> 5, py = tid & 31;        // 16 ch x 32 pooled rows = 512 threads
  float wr[27];
  #pragma unroll
  for (int i = 0; i < 27; i++) wr[i] = swg[ch * 27 + i];
  float bias = bc[ch];
  #pragma unroll
  for (int xt = 0; xt < 64; xt += 32) {    // two x-tiles of 32 conv cols
    float a0[32], a1[32];
    #pragma unroll
    for (int i = 0; i < 32; i++) { a0[i] = 0.f; a1[i] = 0.f; }
    #pragma unroll
    for (int c = 0; c < 3; c++) {
      const float* wc = wr + c * 9;
      #pragma unroll
      for (int r = 0; r < 4; r++) {        // padded input rows 2py+r
        const float* rp = &crop[c][2 * py + r][xt];
        float win[36];
        #pragma unroll
        for (int v = 0; v < 9; v++) {
          float4 q = *(const float4*)(rp + v * 4);
          win[v * 4 + 0] = q.x; win[v * 4 + 1] = q.y;
          win[v * 4 + 2] = q.z; win[v * 4 + 3] = q.w;
        }
        if (r == 0) {
          #pragma unroll
          for (int x = 0; x < 32; x++)
            a0[x] += win[x] * wc[0] + win[x + 1] * wc[1] + win[x + 2] * wc[2];
        } else if (r == 1) {
          #pragma unroll
          for (int x = 0; x < 32; x++) {
            a0[x] += win[x] * wc[3] + win[x + 1] * wc[4] + win[x + 2] * wc[5];
            a1[x] += win[x] * wc[0] + win[x + 1] * wc[1] + win[x + 2] * wc[2];
          }
        } else if (r == 2) {
          #pragma unroll
          for (int x = 0; x < 32; x++) {
            a0[x] += win[x] * wc[6] + win[x + 1] * wc[7] + win[x + 2] * wc[8];
            a1[x] += win[x] * wc[3] + win[x + 1] * wc[4] + win[x + 2] * wc[5];
          }
        } else {
          #pragma unroll
          for (int x = 0; x < 32; x++)
            a1[x] += win[x] * wc[6] + win[x + 1] * wc[7] + win[x + 2] * wc[8];
        }
      }
    }
    size_t base = (size_t)det * 16384 + ch * 1024 + py * 32 + (xt >> 1);
    #pragma unroll
    for (int i = 0; i < 16; i++) {
      float m = fmaxf(fmaxf(a0[2 * i], a0[2 * i + 1]), fmaxf(a1[2 * i], a1[2 * i + 1]));
      feats[base + i] = (short)f2bf(fmaxf(m + bias, 0.f));
    }
  }
}

// W1 [8][16384][128] f32 -> W1t [8][128][16384] bf16
__global__ __launch_bounds__(256) void k_w1t(const float* __restrict__ W1,
                                             short* __restrict__ w1t) {
  __shared__ float tile[128][33];
  int bx = blockIdx.x, by = blockIdx.y, bz = blockIdx.z;  // ftile(128f), dtile(32d), head
  int t = threadIdx.x;
  const size_t hbase = (size_t)bz * 16384;
  #pragma unroll
  for (int i = 0; i < 16; i++) {
    int u = t + i * 256;
    int fl = u >> 5, dl = u & 31;
    tile[fl][dl] = W1[(hbase + bx * 128 + fl) * 128 + by * 32 + dl];
  }
  __syncthreads();
  #pragma unroll
  for (int i = 0; i < 16; i++) {
    int u = t + i * 256;
    int dl = u >> 7, fl = u & 127;
    w1t[((size_t)bz * 128 + by * 32 + dl) * 16384 + bx * 128 + fl] = (short)f2bf(tile[fl][dl]);
  }
}

// feats[320][16384] bf16  x  W1t[head][128][16384] bf16 -> partial f32 (split-K)
__global__ __launch_bounds__(256) void k_gemm(const short* __restrict__ feats,
                                              const short* __restrict__ w1t,
                                              float* __restrict__ part) {
  __shared__ short As[64][72];    // [m][k] pad->144B rows (16B aligned)
  __shared__ short Bs[128][72];   // [n][k]
  int tid = threadIdx.x;
  int wv = tid >> 6, lane = tid & 63;
  int m0 = blockIdx.x * 64;
  int by = blockIdx.y, bz = blockIdx.z;   // head, ksplit
  f32x4 acc[8];
  #pragma unroll
  for (int i = 0; i < 8; i++) acc[i] = (f32x4){0.f, 0.f, 0.f, 0.f};
  int lr = lane & 15, kg = lane >> 4;
  for (int it = 0; it < 32; ++it) {
    int f0 = bz * 2048 + it * 64;
    __syncthreads();
    #pragma unroll
    for (int i = 0; i < 2; i++) {
      int u = tid + i * 256, row = u >> 3, c16 = u & 7;
      *(s16x8*)&As[row][c16 * 8] =
          *(const s16x8*)(feats + (size_t)(m0 + row) * 16384 + f0 + c16 * 8);
    }
    #pragma unroll
    for (int i = 0; i < 4; i++) {
      int u = tid + i * 256, row = u >> 3, c16 = u & 7;
      *(s16x8*)&Bs[row][c16 * 8] =
          *(const s16x8*)(w1t + ((size_t)by * 128 + row) * 16384 + f0 + c16 * 8);
    }
    __syncthreads();
    #pragma unroll
    for (int kk = 0; kk < 64; kk += 32) {
      s16x8 a = *(s16x8*)&As[wv * 16 + lr][kk + kg * 8];
      #pragma unroll
      for (int nf = 0; nf < 8; nf++) {
        s16x8 b = *(s16x8*)&Bs[nf * 16 + lr][kk + kg * 8];
        acc[nf] = __builtin_amdgcn_mfma_f32_16x16x32_bf16(a, b, acc[nf], 0, 0, 0);
      }
    }
  }
  #pragma unroll
  for (int nf = 0; nf < 8; nf++) {
    #pragma unroll
    for (int j = 0; j < 4; j++) {
      int m = m0 + wv * 16 + kg * 4 + j;   // C/D: row=(lane>>4)*4+j, col=lane&15
      int d = nf * 16 + lr;
      part[(((size_t)bz * 8 + by) * 320 + m) * 128 + d] = acc[nf][j];
    }
  }
}

__global__ __launch_bounds__(256) void k_reduce(const float* __restrict__ part,
                                                const float* __restrict__ b1,
                                                float* __restrict__ h) {
  int o = blockIdx.x * 256 + threadIdx.x;    // 8*300*128 = 307200
  int d = o & 127;
  int k = (o >> 7) % 300;
  int hh = o / (128 * 300);
  float s = 0.f;
  #pragma unroll
  for (int ks = 0; ks < 8; ks++)
    s += part[(((size_t)ks * 8 + hh) * 320 + k) * 128 + d];
  s += b1[hh * 128 + d];
  h[o] = fmaxf(s, 0.f);
}

__global__ __launch_bounds__(320) void k_fc2(const float* __restrict__ h,
                                             const float* __restrict__ keepf,
                                             const float* __restrict__ W2p,
                                             const float* __restrict__ b2p,
                                             const float* __restrict__ W2a,
                                             const float* __restrict__ b2a,
                                             const float* __restrict__ W2d,
                                             const float* __restrict__ b2d,
                                             float* __restrict__ out) {
  int det = blockIdx.x, t = threadIdx.x;
  __shared__ float hl[1024];
  for (int i = t; i < 1024; i += 320) {
    int hh = i >> 7, d = i & 127;
    hl[i] = h[((size_t)hh * 300 + det) * 128 + d];
  }
  __syncthreads();
  if (t >= 273) return;
  float kf = keepf[det];
  float s = 0.f, bias;
  if (t < 38) {
    const float* hp = hl;                        // head 0
    for (int d = 0; d < 128; d++) s += hp[d] * W2p[d * 38 + t];
    bias = b2p[t];
  } else if (t < 63) {
    int c = t - 38;
    const float* hp = hl + 128;                  // head 1
    for (int d = 0; d < 128; d++) s += hp[d] * W2a[d * 25 + c];
    bias = b2a[c];
  } else {
    int u = t - 63, j = u / 35, o = u - j * 35;
    const float* hp = hl + (2 + j) * 128;        // heads 2..7
    for (int d = 0; d < 128; d++) s += hp[d] * W2d[((size_t)j * 128 + d) * 35 + o];
    bias = b2d[j * 35 + o];
  }
  out[det * 273 + t] = (s + bias) * kf;
}

extern "C" void kernel_launch(void* const* d_in, const int* in_sizes, int n_in,
                              void* d_out, int out_size, void* d_ws, size_t ws_size,
                              hipStream_t stream) {
  (void)in_sizes; (void)n_in; (void)out_size; (void)ws_size;
  const float* preds = (const float*)d_in[0];
  const float* image = (const float*)d_in[1];
  const float* Wc    = (const float*)d_in[2];
  const float* bc    = (const float*)d_in[3];
  const float* W1    = (const float*)d_in[4];
  const float* b1    = (const float*)d_in[5];
  const float* W2p   = (const float*)d_in[6];
  const float* b2p   = (const float*)d_in[7];
  const float* W2a   = (const float*)d_in[8];
  const float* b2a   = (const float*)d_in[9];
  const float* W2d   = (const float*)d_in[10];
  const float* b2d   = (const float*)d_in[11];

  char* ws = (char*)d_ws;
  unsigned* hist   = (unsigned*)(ws + OFF_HIST);
  unsigned* cnt    = (unsigned*)(ws + OFF_CNT);
  unsigned* cut    = (unsigned*)(ws + OFF_CUT);
  u64*      cand   = (u64*)(ws + OFF_CAND);
  float*    boxes  = (float*)(ws + OFF_BOXES);
  int*      xy1    = (int*)(ws + OFF_XY1);
  float*    validf = (float*)(ws + OFF_VALID);
  float*    keepf  = (float*)(ws + OFF_KEEP);
  u64*      sup    = (u64*)(ws + OFF_SUP);
  float*    hbuf   = (float*)(ws + OFF_H);
  short*    feats  = (short*)(ws + OFF_FEATS);
  short*    w1t    = (short*)(ws + OFF_W1T);
  float*    part   = (float*)(ws + OFF_PART);
  float*    out    = (float*)d_out;

  hipMemsetAsync(ws, 0, CTRL_BYTES, stream);
  k_hist<<<(N_PRED + 255) / 256, 256, 0, stream>>>(preds, hist);
  k_findcut<<<1, 256, 0, stream>>>(hist, cut);
  k_compact<<<(N_PRED + 255) / 256, 256, 0, stream>>>(preds, cut, cnt, cand);
  k_sortprep<<<1, 1024, 0, stream>>>(preds, cand, boxes, xy1, validf);
  k_iou<<<MAXD, 64, 0, stream>>>(boxes, sup);
  k_nms<<<1, 64, 0, stream>>>(sup, validf, keepf);
  k_cropconv<<<320, 512, 0, stream>>>(image, Wc, bc, xy1, feats);
  k_w1t<<<dim3(128, 4, 8), 256, 0, stream>>>(W1, w1t);
  k_gemm<<<dim3(5, 8, 8), 256, 0, stream>>>(feats, w1t, part);
  k_reduce<<<1200, 256, 0, stream>>>(part, b1, hbuf);
  k_fc2<<<MAXD, 320, 0, stream>>>(hbuf, keepf, W2p, b2p, W2a, b2a, W2d, b2d, out);
}

// Round 2
// 281.709 us; speedup vs baseline: 1.2368x; 1.2368x over previous
//
#include <hip/hip_runtime.h>

#define N_PRED 25200
#define CONF 0.25f
#define IOU_THR 0.45f
#define MAXD 300
#define IMGW 640
#define CROPW 64
#define HISTN 16640

typedef float f32x4 __attribute__((ext_vector_type(4)));
typedef short s16x8 __attribute__((ext_vector_type(8)));
typedef unsigned long long u64;

// ---- workspace layout (bytes) ----
#define OFF_HIST   0u            // 16640*4 = 66560
#define OFF_CNT    66560u        // counters (cnt at +0)
#define OFF_CUT    66624u
#define OFF_CAND   66816u        // 1024 * 8 = 8192
#define CTRL_BYTES 75008u        // memset [0, CTRL_BYTES) each call
#define OFF_BOXES  75008u        // 300*4*4
#define OFF_XY1    79872u        // 300*2*4
#define OFF_VALID  82432u        // 300*4
#define OFF_KEEP   83712u        // 300*4
#define OFF_H      97024u        // 8*300*128*4 = 1228800
#define OFF_FEATS  1325824u      // 320*16384*2 = 10485760
#define OFF_W1T    11811584u     // 8*128*16384*2 = 33554432
#define OFF_PART   45366016u     // 8*8*320*128*4 = 13107200

__device__ inline unsigned short f2bf(float x) {
  unsigned u = __float_as_uint(x);
  u += 0x7FFFu + ((u >> 16) & 1u);   // round-to-nearest-even
  return (unsigned short)(u >> 16);
}

// ---------------- stage 1: score histogram (radix cut for top-300) -------
__global__ __launch_bounds__(256) void k_hist(const float* __restrict__ preds,
                                              unsigned* __restrict__ hist) {
  int i = blockIdx.x * 256 + threadIdx.x;
  if (i >= N_PRED) return;
  float s = preds[i * 6 + 4] * preds[i * 6 + 5];
  if (s > CONF) atomicAdd(&hist[__float_as_uint(s) >> 16], 1u);
}

// find largest bucket b with suffix-count(b) >= 300 (single scan pass)
__global__ __launch_bounds__(256) void k_findcut(const unsigned* __restrict__ hist,
                                                 unsigned* __restrict__ cut) {
  __shared__ unsigned s[256];
  int t = threadIdx.x;
  int base = t * 65;                       // 256*65 = 16640
  unsigned local = 0;
  for (int i = 0; i < 65; ++i) local += hist[base + i];
  s[t] = local;
  __syncthreads();
  for (int off = 1; off < 256; off <<= 1) {   // inclusive suffix scan
    unsigned add = (t + off < 256) ? s[t + off] : 0u;
    __syncthreads();
    s[t] += add;
    __syncthreads();
  }
  unsigned incl = s[t];
  unsigned excl = (t < 255) ? s[t + 1] : 0u;
  if (incl >= (unsigned)MAXD && excl < (unsigned)MAXD) {   // unique owning thread
    unsigned acc = excl, res = 0u;
    #pragma unroll
    for (int ii = 64; ii >= 0; --ii) {
      acc += hist[base + ii];
      if (res == 0u && acc >= (unsigned)MAXD) res = (unsigned)(base + ii);
    }
    cut[0] = res;
  }
  // if total < 300 no thread writes; cut stays 0 from memset.
}

__global__ __launch_bounds__(256) void k_compact(const float* __restrict__ preds,
                                                 const unsigned* __restrict__ cut,
                                                 unsigned* __restrict__ cnt,
                                                 u64* __restrict__ cand) {
  int i = blockIdx.x * 256 + threadIdx.x;
  if (i >= N_PRED) return;
  float s = preds[i * 6 + 4] * preds[i * 6 + 5];
  if (s <= CONF) return;
  unsigned bits = __float_as_uint(s);
  if ((bits >> 16) < cut[0]) return;
  unsigned pos = atomicAdd(cnt, 1u);
  if (pos < 1024u)
    cand[pos] = ((u64)bits << 32) | (u64)(0xFFFFFFFFu - (unsigned)i);  // ties: lower idx first
}

// bitonic sort 1024 u64 descending; emit boxes / crop coords / valid flags
__global__ __launch_bounds__(1024) void k_sortprep(const float* __restrict__ preds,
                                                   const u64* __restrict__ cand,
                                                   float* __restrict__ boxes,
                                                   int* __restrict__ xy1,
                                                   float* __restrict__ validf) {
  __shared__ u64 sk[1024];
  int t = threadIdx.x;
  sk[t] = cand[t];
  __syncthreads();
  for (int k = 2; k <= 1024; k <<= 1)
    for (int j = k >> 1; j > 0; j >>= 1) {
      int p = t ^ j;
      if (p > t) {
        u64 a = sk[t], b = sk[p];
        bool up = ((t & k) == 0);
        bool sw = up ? (a < b) : (a > b);      // descending overall
        if (sw) { sk[t] = b; sk[p] = a; }
      }
      __syncthreads();
    }
  if (t < MAXD) {
    u64 key = sk[t];
    if (key != 0ull) {
      int idx = (int)(0xFFFFFFFFu - (unsigned)(key & 0xFFFFFFFFull));
      float cx = preds[idx * 6 + 0], cy = preds[idx * 6 + 1];
      float w  = preds[idx * 6 + 2], h  = preds[idx * 6 + 3];
      float x1 = cx - w * 0.5f, y1 = cy - h * 0.5f;
      float x2 = cx + w * 0.5f, y2 = cy + h * 0.5f;
      boxes[t * 4 + 0] = x1; boxes[t * 4 + 1] = y1;
      boxes[t * 4 + 2] = x2; boxes[t * 4 + 3] = y2;
      int xi = (int)rintf(x1); xi = min(max(xi, 0), IMGW - CROPW);
      int yi = (int)rintf(y1); yi = min(max(yi, 0), IMGW - CROPW);
      xy1[t * 2 + 0] = xi; xy1[t * 2 + 1] = yi;
      validf[t] = 1.0f;
    } else {
      boxes[t * 4 + 0] = 0.f; boxes[t * 4 + 1] = 0.f;
      boxes[t * 4 + 2] = 0.f; boxes[t * 4 + 3] = 0.f;
      xy1[t * 2 + 0] = 0; xy1[t * 2 + 1] = 0;
      validf[t] = 0.f;
    }
  }
}

// fused IoU-matrix + greedy NMS: one block, 5 waves.
// Waves build 300x300 suppression bitmask in LDS via ballots; wave 0 runs the
// sequential recurrence chunked by 64 entirely in registers (no memory on the
// critical path). IoU symmetry => row i's mask == column i's suppression set.
__global__ __launch_bounds__(320) void k_iou_nms(const float* __restrict__ boxes,
                                                 const float* __restrict__ validf,
                                                 float* __restrict__ keepf) {
  __shared__ float sb[MAXD][4];
  __shared__ u64 sup[MAXD][5];
  __shared__ u64 skw[5];
  int t = threadIdx.x;
  int w = t >> 6, lane = t & 63;
  for (int i = t; i < MAXD * 4; i += 320) ((float*)sb)[i] = boxes[i];
  __syncthreads();
  int j = t;                                 // my column (0..319)
  float bx1 = 0.f, by1 = 0.f, bx2 = 0.f, by2 = 0.f, arj = 0.f;
  if (j < MAXD) {
    bx1 = sb[j][0]; by1 = sb[j][1]; bx2 = sb[j][2]; by2 = sb[j][3];
    arj = (bx2 - bx1) * (by2 - by1);
  }
  for (int i = 0; i < MAXD; ++i) {
    float x1 = sb[i][0], y1 = sb[i][1], x2 = sb[i][2], y2 = sb[i][3];
    float ar = (x2 - x1) * (y2 - y1);
    float iw = fmaxf(fminf(x2, bx2) - fmaxf(x1, bx1), 0.f);
    float ih = fmaxf(fminf(y2, by2) - fmaxf(y1, by1), 0.f);
    float inter = iw * ih;
    float iou = inter / (ar + arj - inter + 1e-7f);
    u64 bm = __ballot((j < MAXD) && (iou > IOU_THR));
    if (lane == 0) sup[i][w] = bm;
  }
  __syncthreads();
  if (w == 0) {
    u64 kw0 = 0, kw1 = 0, kw2 = 0, kw3 = 0;   // finalized keep words
    #pragma unroll
    for (int c = 0; c < 5; ++c) {
      int i = c * 64 + lane;
      u64 srow[5];
      #pragma unroll
      for (int ww = 0; ww < 5; ++ww)
        srow[ww] = (ww <= c && i < MAXD) ? sup[i][ww] : 0ull;
      bool ext = ((srow[0] & kw0) | (srow[1] & kw1) | (srow[2] & kw2) | (srow[3] & kw3)) != 0ull;
      bool validme = (i < MAXD) && (validf[i] > 0.5f);
      u64 alive = __ballot(validme && !ext);
      unsigned mlo = (unsigned)srow[c], mhi = (unsigned)(srow[c] >> 32);
      for (int b = 0; b < 64; ++b) {
        if ((alive >> b) & 1ull) {
          u64 mi = ((u64)(unsigned)__shfl((int)mhi, b) << 32) | (u64)(unsigned)__shfl((int)mlo, b);
          if (b < 63) alive &= ~(mi & (~0ull << (b + 1)));
        }
      }
      if (c == 0) kw0 = alive;
      else if (c == 1) kw1 = alive;
      else if (c == 2) kw2 = alive;
      else if (c == 3) kw3 = alive;
      if (lane == 0) skw[c] = alive;
    }
  }
  __syncthreads();
  for (int jj = t; jj < MAXD; jj += 320)
    keepf[jj] = ((skw[jj >> 6] >> (jj & 63)) & 1ull) ? 1.f : 0.f;
}

// crop + 3x3 SAME conv(16) + ReLU + 2x2 maxpool -> feats[det][16384] (bf16)
__global__ __launch_bounds__(512) void k_cropconv(const float* __restrict__ image,
                                                  const float* __restrict__ Wc,
                                                  const float* __restrict__ bc,
                                                  const int* __restrict__ xy1,
                                                  short* __restrict__ feats) {
  int det = blockIdx.x, tid = threadIdx.x;
  if (det >= MAXD) {                       // pad rows 300..319 -> zeros
    for (int i = tid; i < 16384; i += 512) feats[(size_t)det * 16384 + i] = 0;
    return;
  }
  __shared__ float crop[3][66][68];        // zero-padded crop
  __shared__ float swg[432];
  for (int i = tid; i < 3 * 66 * 68; i += 512) ((float*)crop)[i] = 0.f;
  for (int i = tid; i < 432; i += 512) swg[i] = Wc[i];
  __syncthreads();
  int x0 = xy1[det * 2 + 0], y0 = xy1[det * 2 + 1];
  for (int i = tid; i < 3 * 64 * 64; i += 512) {
    int c = i >> 12, rem = i & 4095, y = rem >> 6, x = rem & 63;
    crop[c][y + 1][x + 1] = image[(size_t)c * (IMGW * IMGW) + (y0 + y) * IMGW + (x0 + x)];
  }
  __syncthreads();
  int ch = tid >> 5, py = tid & 31;        // 16 ch x 32 pooled rows = 512 threads
  float wr[27];
  #pragma unroll
  for (int i = 0; i < 27; i++) wr[i] = swg[ch * 27 + i];
  float bias = bc[ch];
  #pragma unroll
  for (int xt = 0; xt < 64; xt += 32) {    // two x-tiles of 32 conv cols
    float a0[32], a1[32];
    #pragma unroll
    for (int i = 0; i < 32; i++) { a0[i] = 0.f; a1[i] = 0.f; }
    #pragma unroll
    for (int c = 0; c < 3; c++) {
      const float* wc = wr + c * 9;
      #pragma unroll
      for (int r = 0; r < 4; r++) {        // padded input rows 2py+r
        const float* rp = &crop[c][2 * py + r][xt];
        float win[36];
        #pragma unroll
        for (int v = 0; v < 9; v++) {
          float4 q = *(const float4*)(rp + v * 4);
          win[v * 4 + 0] = q.x; win[v * 4 + 1] = q.y;
          win[v * 4 + 2] = q.z; win[v * 4 + 3] = q.w;
        }
        if (r == 0) {
          #pragma unroll
          for (int x = 0; x < 32; x++)
            a0[x] += win[x] * wc[0] + win[x + 1] * wc[1] + win[x + 2] * wc[2];
        } else if (r == 1) {
          #pragma unroll
          for (int x = 0; x < 32; x++) {
            a0[x] += win[x] * wc[3] + win[x + 1] * wc[4] + win[x + 2] * wc[5];
            a1[x] += win[x] * wc[0] + win[x + 1] * wc[1] + win[x + 2] * wc[2];
          }
        } else if (r == 2) {
          #pragma unroll
          for (int x = 0; x < 32; x++) {
            a0[x] += win[x] * wc[6] + win[x + 1] * wc[7] + win[x + 2] * wc[8];
            a1[x] += win[x] * wc[3] + win[x + 1] * wc[4] + win[x + 2] * wc[5];
          }
        } else {
          #pragma unroll
          for (int x = 0; x < 32; x++)
            a1[x] += win[x] * wc[6] + win[x + 1] * wc[7] + win[x + 2] * wc[8];
        }
      }
    }
    size_t base = (size_t)det * 16384 + ch * 1024 + py * 32 + (xt >> 1);
    #pragma unroll
    for (int i = 0; i < 16; i++) {
      float m = fmaxf(fmaxf(a0[2 * i], a0[2 * i + 1]), fmaxf(a1[2 * i], a1[2 * i + 1]));
      feats[base + i] = (short)f2bf(fmaxf(m + bias, 0.f));
    }
  }
}

// W1 [8][16384][128] f32 -> W1t [8][128][16384] bf16
__global__ __launch_bounds__(256) void k_w1t(const float* __restrict__ W1,
                                             short* __restrict__ w1t) {
  __shared__ float tile[128][33];
  int bx = blockIdx.x, by = blockIdx.y, bz = blockIdx.z;  // ftile(128f), dtile(32d), head
  int t = threadIdx.x;
  const size_t hbase = (size_t)bz * 16384;
  #pragma unroll
  for (int i = 0; i < 16; i++) {
    int u = t + i * 256;
    int fl = u >> 5, dl = u & 31;
    tile[fl][dl] = W1[(hbase + bx * 128 + fl) * 128 + by * 32 + dl];
  }
  __syncthreads();
  #pragma unroll
  for (int i = 0; i < 16; i++) {
    int u = t + i * 256;
    int dl = u >> 7, fl = u & 127;
    w1t[((size_t)bz * 128 + by * 32 + dl) * 16384 + bx * 128 + fl] = (short)f2bf(tile[fl][dl]);
  }
}

// feats[320][16384] bf16  x  W1t[head][128][16384] bf16 -> partial f32 (split-K)
__global__ __launch_bounds__(256) void k_gemm(const short* __restrict__ feats,
                                              const short* __restrict__ w1t,
                                              float* __restrict__ part) {
  __shared__ short As[64][72];    // [m][k] pad->144B rows (16B aligned)
  __shared__ short Bs[128][72];   // [n][k]
  int tid = threadIdx.x;
  int wv = tid >> 6, lane = tid & 63;
  int m0 = blockIdx.x * 64;
  int by = blockIdx.y, bz = blockIdx.z;   // head, ksplit
  f32x4 acc[8];
  #pragma unroll
  for (int i = 0; i < 8; i++) acc[i] = (f32x4){0.f, 0.f, 0.f, 0.f};
  int lr = lane & 15, kg = lane >> 4;
  for (int it = 0; it < 32; ++it) {
    int f0 = bz * 2048 + it * 64;
    __syncthreads();
    #pragma unroll
    for (int i = 0; i < 2; i++) {
      int u = tid + i * 256, row = u >> 3, c16 = u & 7;
      *(s16x8*)&As[row][c16 * 8] =
          *(const s16x8*)(feats + (size_t)(m0 + row) * 16384 + f0 + c16 * 8);
    }
    #pragma unroll
    for (int i = 0; i < 4; i++) {
      int u = tid + i * 256, row = u >> 3, c16 = u & 7;
      *(s16x8*)&Bs[row][c16 * 8] =
          *(const s16x8*)(w1t + ((size_t)by * 128 + row) * 16384 + f0 + c16 * 8);
    }
    __syncthreads();
    #pragma unroll
    for (int kk = 0; kk < 64; kk += 32) {
      s16x8 a = *(s16x8*)&As[wv * 16 + lr][kk + kg * 8];
      #pragma unroll
      for (int nf = 0; nf < 8; nf++) {
        s16x8 b = *(s16x8*)&Bs[nf * 16 + lr][kk + kg * 8];
        acc[nf] = __builtin_amdgcn_mfma_f32_16x16x32_bf16(a, b, acc[nf], 0, 0, 0);
      }
    }
  }
  #pragma unroll
  for (int nf = 0; nf < 8; nf++) {
    #pragma unroll
    for (int j = 0; j < 4; j++) {
      int m = m0 + wv * 16 + kg * 4 + j;   // C/D: row=(lane>>4)*4+j, col=lane&15
      int d = nf * 16 + lr;
      part[(((size_t)bz * 8 + by) * 320 + m) * 128 + d] = acc[nf][j];
    }
  }
}

__global__ __launch_bounds__(256) void k_reduce(const float* __restrict__ part,
                                                const float* __restrict__ b1,
                                                float* __restrict__ h) {
  int o = blockIdx.x * 256 + threadIdx.x;    // 8*300*128 = 307200
  int d = o & 127;
  int k = (o >> 7) % 300;
  int hh = o / (128 * 300);
  float s = 0.f;
  #pragma unroll
  for (int ks = 0; ks < 8; ks++)
    s += part[(((size_t)ks * 8 + hh) * 320 + k) * 128 + d];
  s += b1[hh * 128 + d];
  h[o] = fmaxf(s, 0.f);
}

__global__ __launch_bounds__(320) void k_fc2(const float* __restrict__ h,
                                             const float* __restrict__ keepf,
                                             const float* __restrict__ W2p,
                                             const float* __restrict__ b2p,
                                             const float* __restrict__ W2a,
                                             const float* __restrict__ b2a,
                                             const float* __restrict__ W2d,
                                             const float* __restrict__ b2d,
                                             float* __restrict__ out) {
  int det = blockIdx.x, t = threadIdx.x;
  __shared__ float hl[1024];
  for (int i = t; i < 1024; i += 320) {
    int hh = i >> 7, d = i & 127;
    hl[i] = h[((size_t)hh * 300 + det) * 128 + d];
  }
  __syncthreads();
  if (t >= 273) return;
  float kf = keepf[det];
  float s = 0.f, bias;
  if (t < 38) {
    const float* hp = hl;                        // head 0
    for (int d = 0; d < 128; d++) s += hp[d] * W2p[d * 38 + t];
    bias = b2p[t];
  } else if (t < 63) {
    int c = t - 38;
    const float* hp = hl + 128;                  // head 1
    for (int d = 0; d < 128; d++) s += hp[d] * W2a[d * 25 + c];
    bias = b2a[c];
  } else {
    int u = t - 63, j = u / 35, o = u - j * 35;
    const float* hp = hl + (2 + j) * 128;        // heads 2..7
    for (int d = 0; d < 128; d++) s += hp[d] * W2d[((size_t)j * 128 + d) * 35 + o];
    bias = b2d[j * 35 + o];
  }
  out[det * 273 + t] = (s + bias) * kf;
}

extern "C" void kernel_launch(void* const* d_in, const int* in_sizes, int n_in,
                              void* d_out, int out_size, void* d_ws, size_t ws_size,
                              hipStream_t stream) {
  (void)in_sizes; (void)n_in; (void)out_size; (void)ws_size;
  const float* preds = (const float*)d_in[0];
  const float* image = (const float*)d_in[1];
  const float* Wc    = (const float*)d_in[2];
  const float* bc    = (const float*)d_in[3];
  const float* W1    = (const float*)d_in[4];
  const float* b1    = (const float*)d_in[5];
  const float* W2p   = (const float*)d_in[6];
  const float* b2p   = (const float*)d_in[7];
  const float* W2a   = (const float*)d_in[8];
  const float* b2a   = (const float*)d_in[9];
  const float* W2d   = (const float*)d_in[10];
  const float* b2d   = (const float*)d_in[11];

  char* ws = (char*)d_ws;
  unsigned* hist   = (unsigned*)(ws + OFF_HIST);
  unsigned* cnt    = (unsigned*)(ws + OFF_CNT);
  unsigned* cut    = (unsigned*)(ws + OFF_CUT);
  u64*      cand   = (u64*)(ws + OFF_CAND);
  float*    boxes  = (float*)(ws + OFF_BOXES);
  int*      xy1    = (int*)(ws + OFF_XY1);
  float*    validf = (float*)(ws + OFF_VALID);
  float*    keepf  = (float*)(ws + OFF_KEEP);
  float*    hbuf   = (float*)(ws + OFF_H);
  short*    feats  = (short*)(ws + OFF_FEATS);
  short*    w1t    = (short*)(ws + OFF_W1T);
  float*    part   = (float*)(ws + OFF_PART);
  float*    out    = (float*)d_out;

  hipMemsetAsync(ws, 0, CTRL_BYTES, stream);
  k_hist<<<(N_PRED + 255) / 256, 256, 0, stream>>>(preds, hist);
  k_findcut<<<1, 256, 0, stream>>>(hist, cut);
  k_compact<<<(N_PRED + 255) / 256, 256, 0, stream>>>(preds, cut, cnt, cand);
  k_sortprep<<<1, 1024, 0, stream>>>(preds, cand, boxes, xy1, validf);
  k_iou_nms<<<1, 320, 0, stream>>>(boxes, validf, keepf);
  k_cropconv<<<320, 512, 0, stream>>>(image, Wc, bc, xy1, feats);
  k_w1t<<<dim3(128, 4, 8), 256, 0, stream>>>(W1, w1t);
  k_gemm<<<dim3(5, 8, 8), 256, 0, stream>>>(feats, w1t, part);
  k_reduce<<<1200, 256, 0, stream>>>(part, b1, hbuf);
  k_fc2<<<MAXD, 320, 0, stream>>>(hbuf, keepf, W2p, b2p, W2a, b2a, W2d, b2d, out);
}

// Round 3
// 251.576 us; speedup vs baseline: 1.3849x; 1.1198x over previous
//
#include <hip/hip_runtime.h>

#define N_PRED 25200
#define CONF 0.25f
#define IOU_THR 0.45f
#define MAXD 300
#define IMGW 640
#define CROPW 64
#define HISTN 16640

typedef float f32x4 __attribute__((ext_vector_type(4)));
typedef short s16x8 __attribute__((ext_vector_type(8)));
typedef unsigned long long u64;

// ---- workspace layout (bytes) ----
#define OFF_HIST   0u            // 16640*4 = 66560
#define OFF_CNT    66560u        // counters (cnt at +0)
#define OFF_CUT    66624u
#define OFF_CAND   66816u        // 1024 * 8 = 8192
#define CTRL_BYTES 75008u        // memset [0, CTRL_BYTES) each call
#define OFF_BOXES  75008u        // 300*4*4
#define OFF_XY1    79872u        // 300*2*4
#define OFF_VALID  82432u        // 300*4
#define OFF_KEEP   83712u        // 300*4
#define OFF_H      97024u        // 8*300*128*4 = 1228800
#define OFF_FEATS  1325824u      // 320*16384*2 = 10485760
#define OFF_W1T    11811584u     // 8*128*16384*2 = 33554432
#define OFF_PART   45366016u     // 8*8*320*128*4 = 13107200

__device__ inline unsigned short f2bf(float x) {
  unsigned u = __float_as_uint(x);
  u += 0x7FFFu + ((u >> 16) & 1u);   // round-to-nearest-even
  return (unsigned short)(u >> 16);
}

// ---------------- stage 1: score histogram (radix cut for top-300) -------
__global__ __launch_bounds__(256) void k_hist(const float* __restrict__ preds,
                                              unsigned* __restrict__ hist) {
  int i = blockIdx.x * 256 + threadIdx.x;
  if (i >= N_PRED) return;
  float s = preds[i * 6 + 4] * preds[i * 6 + 5];
  if (s > CONF) atomicAdd(&hist[__float_as_uint(s) >> 16], 1u);
}

// find largest bucket b with suffix-count(b) >= 300 (single scan pass)
__global__ __launch_bounds__(256) void k_findcut(const unsigned* __restrict__ hist,
                                                 unsigned* __restrict__ cut) {
  __shared__ unsigned s[256];
  int t = threadIdx.x;
  int base = t * 65;                       // 256*65 = 16640
  unsigned local = 0;
  for (int i = 0; i < 65; ++i) local += hist[base + i];
  s[t] = local;
  __syncthreads();
  for (int off = 1; off < 256; off <<= 1) {   // inclusive suffix scan
    unsigned add = (t + off < 256) ? s[t + off] : 0u;
    __syncthreads();
    s[t] += add;
    __syncthreads();
  }
  unsigned incl = s[t];
  unsigned excl = (t < 255) ? s[t + 1] : 0u;
  if (incl >= (unsigned)MAXD && excl < (unsigned)MAXD) {   // unique owning thread
    unsigned acc = excl, res = 0u;
    #pragma unroll
    for (int ii = 64; ii >= 0; --ii) {
      acc += hist[base + ii];
      if (res == 0u && acc >= (unsigned)MAXD) res = (unsigned)(base + ii);
    }
    cut[0] = res;
  }
  // if total < 300 no thread writes; cut stays 0 from memset.
}

__global__ __launch_bounds__(256) void k_compact(const float* __restrict__ preds,
                                                 const unsigned* __restrict__ cut,
                                                 unsigned* __restrict__ cnt,
                                                 u64* __restrict__ cand) {
  int i = blockIdx.x * 256 + threadIdx.x;
  if (i >= N_PRED) return;
  float s = preds[i * 6 + 4] * preds[i * 6 + 5];
  if (s <= CONF) return;
  unsigned bits = __float_as_uint(s);
  if ((bits >> 16) < cut[0]) return;
  unsigned pos = atomicAdd(cnt, 1u);
  if (pos < 1024u)
    cand[pos] = ((u64)bits << 32) | (u64)(0xFFFFFFFFu - (unsigned)i);  // ties: lower idx first
}

// bitonic sort 1024 u64 descending; emit boxes / crop coords / valid flags
__global__ __launch_bounds__(1024) void k_sortprep(const float* __restrict__ preds,
                                                   const u64* __restrict__ cand,
                                                   float* __restrict__ boxes,
                                                   int* __restrict__ xy1,
                                                   float* __restrict__ validf) {
  __shared__ u64 sk[1024];
  int t = threadIdx.x;
  sk[t] = cand[t];
  __syncthreads();
  for (int k = 2; k <= 1024; k <<= 1)
    for (int j = k >> 1; j > 0; j >>= 1) {
      int p = t ^ j;
      if (p > t) {
        u64 a = sk[t], b = sk[p];
        bool up = ((t & k) == 0);
        bool sw = up ? (a < b) : (a > b);      // descending overall
        if (sw) { sk[t] = b; sk[p] = a; }
      }
      __syncthreads();
    }
  if (t < MAXD) {
    u64 key = sk[t];
    if (key != 0ull) {
      int idx = (int)(0xFFFFFFFFu - (unsigned)(key & 0xFFFFFFFFull));
      float cx = preds[idx * 6 + 0], cy = preds[idx * 6 + 1];
      float w  = preds[idx * 6 + 2], h  = preds[idx * 6 + 3];
      float x1 = cx - w * 0.5f, y1 = cy - h * 0.5f;
      float x2 = cx + w * 0.5f, y2 = cy + h * 0.5f;
      boxes[t * 4 + 0] = x1; boxes[t * 4 + 1] = y1;
      boxes[t * 4 + 2] = x2; boxes[t * 4 + 3] = y2;
      int xi = (int)rintf(x1); xi = min(max(xi, 0), IMGW - CROPW);
      int yi = (int)rintf(y1); yi = min(max(yi, 0), IMGW - CROPW);
      xy1[t * 2 + 0] = xi; xy1[t * 2 + 1] = yi;
      validf[t] = 1.0f;
    } else {
      boxes[t * 4 + 0] = 0.f; boxes[t * 4 + 1] = 0.f;
      boxes[t * 4 + 2] = 0.f; boxes[t * 4 + 3] = 0.f;
      xy1[t * 2 + 0] = 0; xy1[t * 2 + 1] = 0;
      validf[t] = 0.f;
    }
  }
}

// fused IoU-matrix + greedy NMS: one block, 5 waves.
__global__ __launch_bounds__(320) void k_iou_nms(const float* __restrict__ boxes,
                                                 const float* __restrict__ validf,
                                                 float* __restrict__ keepf) {
  __shared__ float sb[MAXD][4];
  __shared__ u64 sup[MAXD][5];
  __shared__ u64 skw[5];
  int t = threadIdx.x;
  int w = t >> 6, lane = t & 63;
  for (int i = t; i < MAXD * 4; i += 320) ((float*)sb)[i] = boxes[i];
  __syncthreads();
  int j = t;                                 // my column (0..319)
  float bx1 = 0.f, by1 = 0.f, bx2 = 0.f, by2 = 0.f, arj = 0.f;
  if (j < MAXD) {
    bx1 = sb[j][0]; by1 = sb[j][1]; bx2 = sb[j][2]; by2 = sb[j][3];
    arj = (bx2 - bx1) * (by2 - by1);
  }
  for (int i = 0; i < MAXD; ++i) {
    float x1 = sb[i][0], y1 = sb[i][1], x2 = sb[i][2], y2 = sb[i][3];
    float ar = (x2 - x1) * (y2 - y1);
    float iw = fmaxf(fminf(x2, bx2) - fmaxf(x1, bx1), 0.f);
    float ih = fmaxf(fminf(y2, by2) - fmaxf(y1, by1), 0.f);
    float inter = iw * ih;
    float iou = inter / (ar + arj - inter + 1e-7f);
    u64 bm = __ballot((j < MAXD) && (iou > IOU_THR));
    if (lane == 0) sup[i][w] = bm;
  }
  __syncthreads();
  if (w == 0) {
    u64 kw0 = 0, kw1 = 0, kw2 = 0, kw3 = 0;   // finalized keep words
    #pragma unroll
    for (int c = 0; c < 5; ++c) {
      int i = c * 64 + lane;
      u64 srow[5];
      #pragma unroll
      for (int ww = 0; ww < 5; ++ww)
        srow[ww] = (ww <= c && i < MAXD) ? sup[i][ww] : 0ull;
      bool ext = ((srow[0] & kw0) | (srow[1] & kw1) | (srow[2] & kw2) | (srow[3] & kw3)) != 0ull;
      bool validme = (i < MAXD) && (validf[i] > 0.5f);
      u64 alive = __ballot(validme && !ext);
      unsigned mlo = (unsigned)srow[c], mhi = (unsigned)(srow[c] >> 32);
      for (int b = 0; b < 64; ++b) {
        if ((alive >> b) & 1ull) {
          u64 mi = ((u64)(unsigned)__shfl((int)mhi, b) << 32) | (u64)(unsigned)__shfl((int)mlo, b);
          if (b < 63) alive &= ~(mi & (~0ull << (b + 1)));
        }
      }
      if (c == 0) kw0 = alive;
      else if (c == 1) kw1 = alive;
      else if (c == 2) kw2 = alive;
      else if (c == 3) kw3 = alive;
      if (lane == 0) skw[c] = alive;
    }
  }
  __syncthreads();
  for (int jj = t; jj < MAXD; jj += 320)
    keepf[jj] = ((skw[jj >> 6] >> (jj & 63)) & 1ull) ? 1.f : 0.f;
}

// crop + 3x3 SAME conv(16) + ReLU + 2x2 maxpool -> feats[det][16384] (bf16)
// grid (300, 4): det x row-slice. 256 threads = (ch 0..15) x (px 0..15).
// Lane->x mapping: aligned ds_read_b128, <=2-way banks; weights in registers.
__global__ __launch_bounds__(256) void k_cropconv(const float* __restrict__ image,
                                                  const float* __restrict__ Wc,
                                                  const float* __restrict__ bc,
                                                  const int* __restrict__ xy1,
                                                  short* __restrict__ feats) {
  __shared__ __align__(16) float crop[3][18][68];   // 14688 B, halo slice
  int det = blockIdx.x, sl = blockIdx.y, tid = threadIdx.x;
  int pr0 = sl * 8;                 // pooled rows pr0..pr0+7
  int gyBase = pr0 * 2 - 1;         // global crop row of local ry=0
  for (int i = tid; i < 3 * 18 * 68; i += 256) ((float*)crop)[i] = 0.f;
  __syncthreads();
  int x0 = xy1[det * 2 + 0], y0 = xy1[det * 2 + 1];
  for (int u = tid; u < 3 * 18 * 64; u += 256) {
    int c = u / 1152, rem = u % 1152, ry = rem >> 6, x = rem & 63;
    int gy = gyBase + ry;
    if (gy >= 0 && gy < CROPW)
      crop[c][ry][x + 1] = image[(size_t)c * (IMGW * IMGW) + (y0 + gy) * IMGW + x0 + x];
  }
  int ch = tid >> 4, px = tid & 15;
  float w[27];
  #pragma unroll
  for (int i = 0; i < 27; i++) w[i] = Wc[ch * 27 + i];
  float bias = bc[ch];
  __syncthreads();
  #pragma unroll
  for (int pr = 0; pr < 8; pr++) {
    float acc0[4] = {0.f, 0.f, 0.f, 0.f};
    float acc1[4] = {0.f, 0.f, 0.f, 0.f};
    #pragma unroll
    for (int c = 0; c < 3; c++) {
      #pragma unroll
      for (int r = 0; r < 4; r++) {
        const float* rp = &crop[c][2 * pr + r][4 * px];
        f32x4 a = *(const f32x4*)rp;          // 16B-aligned ds_read_b128
        float e0 = rp[4], e1 = rp[5];
        float in[6] = {a[0], a[1], a[2], a[3], e0, e1};
        if (r <= 2) {                          // conv row 0, kernel row r
          const float w0 = w[c * 9 + r * 3], w1 = w[c * 9 + r * 3 + 1], w2 = w[c * 9 + r * 3 + 2];
          #pragma unroll
          for (int q = 0; q < 4; q++)
            acc0[q] += in[q] * w0 + in[q + 1] * w1 + in[q + 2] * w2;
        }
        if (r >= 1) {                          // conv row 1, kernel row r-1
          const float w0 = w[c * 9 + (r - 1) * 3], w1 = w[c * 9 + (r - 1) * 3 + 1], w2 = w[c * 9 + (r - 1) * 3 + 2];
          #pragma unroll
          for (int q = 0; q < 4; q++)
            acc1[q] += in[q] * w0 + in[q + 1] * w1 + in[q + 2] * w2;
        }
      }
    }
    float m0 = fmaxf(fmaxf(acc0[0], acc0[1]), fmaxf(acc1[0], acc1[1]));
    float m1 = fmaxf(fmaxf(acc0[2], acc0[3]), fmaxf(acc1[2], acc1[3]));
    unsigned lo = f2bf(fmaxf(m0 + bias, 0.f));
    unsigned hi = f2bf(fmaxf(m1 + bias, 0.f));
    *(unsigned*)&feats[(size_t)det * 16384 + ch * 1024 + (pr0 + pr) * 32 + 2 * px] =
        lo | (hi << 16);
  }
}

// W1 [8][16384][128] f32 -> W1t [8][128][16384] bf16
__global__ __launch_bounds__(256) void k_w1t(const float* __restrict__ W1,
                                             short* __restrict__ w1t) {
  __shared__ float tile[128][33];
  int bx = blockIdx.x, by = blockIdx.y, bz = blockIdx.z;  // ftile(128f), dtile(32d), head
  int t = threadIdx.x;
  const size_t hbase = (size_t)bz * 16384;
  #pragma unroll
  for (int i = 0; i < 16; i++) {
    int u = t + i * 256;
    int fl = u >> 5, dl = u & 31;
    tile[fl][dl] = W1[(hbase + bx * 128 + fl) * 128 + by * 32 + dl];
  }
  __syncthreads();
  #pragma unroll
  for (int i = 0; i < 16; i++) {
    int u = t + i * 256;
    int dl = u >> 7, fl = u & 127;
    w1t[((size_t)bz * 128 + by * 32 + dl) * 16384 + bx * 128 + fl] = (short)f2bf(tile[fl][dl]);
  }
}

// feats[320][16384] bf16  x  W1t[head][128][16384] bf16 -> partial f32 (split-K)
__global__ __launch_bounds__(256) void k_gemm(const short* __restrict__ feats,
                                              const short* __restrict__ w1t,
                                              float* __restrict__ part) {
  __shared__ short As[64][72];    // [m][k] pad->144B rows (16B aligned)
  __shared__ short Bs[128][72];   // [n][k]
  int tid = threadIdx.x;
  int wv = tid >> 6, lane = tid & 63;
  int m0 = blockIdx.x * 64;
  int by = blockIdx.y, bz = blockIdx.z;   // head, ksplit
  f32x4 acc[8];
  #pragma unroll
  for (int i = 0; i < 8; i++) acc[i] = (f32x4){0.f, 0.f, 0.f, 0.f};
  int lr = lane & 15, kg = lane >> 4;
  for (int it = 0; it < 32; ++it) {
    int f0 = bz * 2048 + it * 64;
    __syncthreads();
    #pragma unroll
    for (int i = 0; i < 2; i++) {
      int u = tid + i * 256, row = u >> 3, c16 = u & 7;
      *(s16x8*)&As[row][c16 * 8] =
          *(const s16x8*)(feats + (size_t)(m0 + row) * 16384 + f0 + c16 * 8);
    }
    #pragma unroll
    for (int i = 0; i < 4; i++) {
      int u = tid + i * 256, row = u >> 3, c16 = u & 7;
      *(s16x8*)&Bs[row][c16 * 8] =
          *(const s16x8*)(w1t + ((size_t)by * 128 + row) * 16384 + f0 + c16 * 8);
    }
    __syncthreads();
    #pragma unroll
    for (int kk = 0; kk < 64; kk += 32) {
      s16x8 a = *(s16x8*)&As[wv * 16 + lr][kk + kg * 8];
      #pragma unroll
      for (int nf = 0; nf < 8; nf++) {
        s16x8 b = *(s16x8*)&Bs[nf * 16 + lr][kk + kg * 8];
        acc[nf] = __builtin_amdgcn_mfma_f32_16x16x32_bf16(a, b, acc[nf], 0, 0, 0);
      }
    }
  }
  #pragma unroll
  for (int nf = 0; nf < 8; nf++) {
    #pragma unroll
    for (int j = 0; j < 4; j++) {
      int m = m0 + wv * 16 + kg * 4 + j;   // C/D: row=(lane>>4)*4+j, col=lane&15
      int d = nf * 16 + lr;
      part[(((size_t)bz * 8 + by) * 320 + m) * 128 + d] = acc[nf][j];
    }
  }
}

__global__ __launch_bounds__(256) void k_reduce(const float* __restrict__ part,
                                                const float* __restrict__ b1,
                                                float* __restrict__ h) {
  int o = blockIdx.x * 256 + threadIdx.x;    // 8*300*128 = 307200
  int d = o & 127;
  int k = (o >> 7) % 300;
  int hh = o / (128 * 300);
  float s = 0.f;
  #pragma unroll
  for (int ks = 0; ks < 8; ks++)
    s += part[(((size_t)ks * 8 + hh) * 320 + k) * 128 + d];
  s += b1[hh * 128 + d];
  h[o] = fmaxf(s, 0.f);
}

__global__ __launch_bounds__(320) void k_fc2(const float* __restrict__ h,
                                             const float* __restrict__ keepf,
                                             const float* __restrict__ W2p,
                                             const float* __restrict__ b2p,
                                             const float* __restrict__ W2a,
                                             const float* __restrict__ b2a,
                                             const float* __restrict__ W2d,
                                             const float* __restrict__ b2d,
                                             float* __restrict__ out) {
  int det = blockIdx.x, t = threadIdx.x;
  __shared__ float hl[1024];
  for (int i = t; i < 1024; i += 320) {
    int hh = i >> 7, d = i & 127;
    hl[i] = h[((size_t)hh * 300 + det) * 128 + d];
  }
  __syncthreads();
  if (t >= 273) return;
  float kf = keepf[det];
  float s = 0.f, bias;
  if (t < 38) {
    const float* hp = hl;                        // head 0
    for (int d = 0; d < 128; d++) s += hp[d] * W2p[d * 38 + t];
    bias = b2p[t];
  } else if (t < 63) {
    int c = t - 38;
    const float* hp = hl + 128;                  // head 1
    for (int d = 0; d < 128; d++) s += hp[d] * W2a[d * 25 + c];
    bias = b2a[c];
  } else {
    int u = t - 63, j = u / 35, o = u - j * 35;
    const float* hp = hl + (2 + j) * 128;        // heads 2..7
    for (int d = 0; d < 128; d++) s += hp[d] * W2d[((size_t)j * 128 + d) * 35 + o];
    bias = b2d[j * 35 + o];
  }
  out[det * 273 + t] = (s + bias) * kf;
}

extern "C" void kernel_launch(void* const* d_in, const int* in_sizes, int n_in,
                              void* d_out, int out_size, void* d_ws, size_t ws_size,
                              hipStream_t stream) {
  (void)in_sizes; (void)n_in; (void)out_size; (void)ws_size;
  const float* preds = (const float*)d_in[0];
  const float* image = (const float*)d_in[1];
  const float* Wc    = (const float*)d_in[2];
  const float* bc    = (const float*)d_in[3];
  const float* W1    = (const float*)d_in[4];
  const float* b1    = (const float*)d_in[5];
  const float* W2p   = (const float*)d_in[6];
  const float* b2p   = (const float*)d_in[7];
  const float* W2a   = (const float*)d_in[8];
  const float* b2a   = (const float*)d_in[9];
  const float* W2d   = (const float*)d_in[10];
  const float* b2d   = (const float*)d_in[11];

  char* ws = (char*)d_ws;
  unsigned* hist   = (unsigned*)(ws + OFF_HIST);
  unsigned* cnt    = (unsigned*)(ws + OFF_CNT);
  unsigned* cut    = (unsigned*)(ws + OFF_CUT);
  u64*      cand   = (u64*)(ws + OFF_CAND);
  float*    boxes  = (float*)(ws + OFF_BOXES);
  int*      xy1    = (int*)(ws + OFF_XY1);
  float*    validf = (float*)(ws + OFF_VALID);
  float*    keepf  = (float*)(ws + OFF_KEEP);
  float*    hbuf   = (float*)(ws + OFF_H);
  short*    feats  = (short*)(ws + OFF_FEATS);
  short*    w1t    = (short*)(ws + OFF_W1T);
  float*    part   = (float*)(ws + OFF_PART);
  float*    out    = (float*)d_out;

  hipMemsetAsync(ws, 0, CTRL_BYTES, stream);
  k_hist<<<(N_PRED + 255) / 256, 256, 0, stream>>>(preds, hist);
  k_findcut<<<1, 256, 0, stream>>>(hist, cut);
  k_compact<<<(N_PRED + 255) / 256, 256, 0, stream>>>(preds, cut, cnt, cand);
  k_sortprep<<<1, 1024, 0, stream>>>(preds, cand, boxes, xy1, validf);
  k_iou_nms<<<1, 320, 0, stream>>>(boxes, validf, keepf);
  k_cropconv<<<dim3(300, 4), 256, 0, stream>>>(image, Wc, bc, xy1, feats);
  k_w1t<<<dim3(128, 4, 8), 256, 0, stream>>>(W1, w1t);
  k_gemm<<<dim3(5, 8, 8), 256, 0, stream>>>(feats, w1t, part);
  k_reduce<<<1200, 256, 0, stream>>>(part, b1, hbuf);
  k_fc2<<<MAXD, 320, 0, stream>>>(hbuf, keepf, W2p, b2p, W2a, b2a, W2d, b2d, out);
}

// Round 5
// 184.168 us; speedup vs baseline: 1.8918x; 1.3660x over previous
//
#include <hip/hip_runtime.h>

#define N_PRED 25200
#define CONF 0.25f
#define IOU_THR 0.45f
#define MAXD 300
#define IMGW 640
#define CROPW 64
#define HISTN 16640
#define KSPLIT 16

typedef float f32x4 __attribute__((ext_vector_type(4)));
typedef short s16x8 __attribute__((ext_vector_type(8)));
typedef unsigned long long u64;

// ---- workspace layout (bytes) ----
#define OFF_HIST   0u            // 16640*4 = 66560
#define OFF_CNT    66560u        // counters (cnt at +0)
#define OFF_CUT    66624u
#define OFF_CAND   66816u        // 1024 * 8 = 8192
#define CTRL_BYTES 75008u        // memset [0, CTRL_BYTES) each call
#define OFF_BOXES  75008u        // 300*4*4
#define OFF_XY1    79872u        // 300*2*4
#define OFF_VALID  82432u        // 300*4
#define OFF_KEEP   83712u        // 300*4
#define OFF_H      97024u        // 8*300*128*4 = 1228800
#define OFF_FEATS  1325824u      // 320*16384*2 = 10485760
#define OFF_PART   11811584u     // 16*8*320*128*4 = 26214400 (ends ~38MB)

__device__ inline unsigned short f2bf(float x) {
  unsigned u = __float_as_uint(x);
  u += 0x7FFFu + ((u >> 16) & 1u);   // round-to-nearest-even
  return (unsigned short)(u >> 16);
}

// ---------------- stage 1: score histogram (radix cut for top-300) -------
__global__ __launch_bounds__(256) void k_hist(const float* __restrict__ preds,
                                              unsigned* __restrict__ hist) {
  int i = blockIdx.x * 256 + threadIdx.x;
  if (i >= N_PRED) return;
  float s = preds[i * 6 + 4] * preds[i * 6 + 5];
  if (s > CONF) atomicAdd(&hist[__float_as_uint(s) >> 16], 1u);
}

// find largest bucket b with suffix-count(b) >= 300 (single scan pass)
__global__ __launch_bounds__(256) void k_findcut(const unsigned* __restrict__ hist,
                                                 unsigned* __restrict__ cut) {
  __shared__ unsigned s[256];
  int t = threadIdx.x;
  int base = t * 65;                       // 256*65 = 16640
  unsigned local = 0;
  for (int i = 0; i < 65; ++i) local += hist[base + i];
  s[t] = local;
  __syncthreads();
  for (int off = 1; off < 256; off <<= 1) {   // inclusive suffix scan
    unsigned add = (t + off < 256) ? s[t + off] : 0u;
    __syncthreads();
    s[t] += add;
    __syncthreads();
  }
  unsigned incl = s[t];
  unsigned excl = (t < 255) ? s[t + 1] : 0u;
  if (incl >= (unsigned)MAXD && excl < (unsigned)MAXD) {   // unique owning thread
    unsigned acc = excl, res = 0u;
    #pragma unroll
    for (int ii = 64; ii >= 0; --ii) {
      acc += hist[base + ii];
      if (res == 0u && acc >= (unsigned)MAXD) res = (unsigned)(base + ii);
    }
    cut[0] = res;
  }
}

__global__ __launch_bounds__(256) void k_compact(const float* __restrict__ preds,
                                                 const unsigned* __restrict__ cut,
                                                 unsigned* __restrict__ cnt,
                                                 u64* __restrict__ cand) {
  int i = blockIdx.x * 256 + threadIdx.x;
  if (i >= N_PRED) return;
  float s = preds[i * 6 + 4] * preds[i * 6 + 5];
  if (s <= CONF) return;
  unsigned bits = __float_as_uint(s);
  if ((bits >> 16) < cut[0]) return;
  unsigned pos = atomicAdd(cnt, 1u);
  if (pos < 1024u)
    cand[pos] = ((u64)bits << 32) | (u64)(0xFFFFFFFFu - (unsigned)i);  // ties: lower idx first
}

// bitonic sort 1024 u64 descending; emit boxes / crop coords / valid flags
__global__ __launch_bounds__(1024) void k_sortprep(const float* __restrict__ preds,
                                                   const u64* __restrict__ cand,
                                                   float* __restrict__ boxes,
                                                   int* __restrict__ xy1,
                                                   float* __restrict__ validf) {
  __shared__ u64 sk[1024];
  int t = threadIdx.x;
  sk[t] = cand[t];
  __syncthreads();
  for (int k = 2; k <= 1024; k <<= 1)
    for (int j = k >> 1; j > 0; j >>= 1) {
      int p = t ^ j;
      if (p > t) {
        u64 a = sk[t], b = sk[p];
        bool up = ((t & k) == 0);
        bool sw = up ? (a < b) : (a > b);      // descending overall
        if (sw) { sk[t] = b; sk[p] = a; }
      }
      __syncthreads();
    }
  if (t < MAXD) {
    u64 key = sk[t];
    if (key != 0ull) {
      int idx = (int)(0xFFFFFFFFu - (unsigned)(key & 0xFFFFFFFFull));
      float cx = preds[idx * 6 + 0], cy = preds[idx * 6 + 1];
      float w  = preds[idx * 6 + 2], h  = preds[idx * 6 + 3];
      float x1 = cx - w * 0.5f, y1 = cy - h * 0.5f;
      float x2 = cx + w * 0.5f, y2 = cy + h * 0.5f;
      boxes[t * 4 + 0] = x1; boxes[t * 4 + 1] = y1;
      boxes[t * 4 + 2] = x2; boxes[t * 4 + 3] = y2;
      int xi = (int)rintf(x1); xi = min(max(xi, 0), IMGW - CROPW);
      int yi = (int)rintf(y1); yi = min(max(yi, 0), IMGW - CROPW);
      xy1[t * 2 + 0] = xi; xy1[t * 2 + 1] = yi;
      validf[t] = 1.0f;
    } else {
      boxes[t * 4 + 0] = 0.f; boxes[t * 4 + 1] = 0.f;
      boxes[t * 4 + 2] = 0.f; boxes[t * 4 + 3] = 0.f;
      xy1[t * 2 + 0] = 0; xy1[t * 2 + 1] = 0;
      validf[t] = 0.f;
    }
  }
}

// fused IoU-matrix + greedy NMS: one block, 5 waves.
__global__ __launch_bounds__(320) void k_iou_nms(const float* __restrict__ boxes,
                                                 const float* __restrict__ validf,
                                                 float* __restrict__ keepf) {
  __shared__ float sb[MAXD][4];
  __shared__ u64 sup[MAXD][5];
  __shared__ u64 skw[5];
  int t = threadIdx.x;
  int w = t >> 6, lane = t & 63;
  for (int i = t; i < MAXD * 4; i += 320) ((float*)sb)[i] = boxes[i];
  __syncthreads();
  int j = t;                                 // my column (0..319)
  float bx1 = 0.f, by1 = 0.f, bx2 = 0.f, by2 = 0.f, arj = 0.f;
  if (j < MAXD) {
    bx1 = sb[j][0]; by1 = sb[j][1]; bx2 = sb[j][2]; by2 = sb[j][3];
    arj = (bx2 - bx1) * (by2 - by1);
  }
  for (int i = 0; i < MAXD; ++i) {
    float x1 = sb[i][0], y1 = sb[i][1], x2 = sb[i][2], y2 = sb[i][3];
    float ar = (x2 - x1) * (y2 - y1);
    float iw = fmaxf(fminf(x2, bx2) - fmaxf(x1, bx1), 0.f);
    float ih = fmaxf(fminf(y2, by2) - fmaxf(y1, by1), 0.f);
    float inter = iw * ih;
    float iou = inter / (ar + arj - inter + 1e-7f);
    u64 bm = __ballot((j < MAXD) && (iou > IOU_THR));
    if (lane == 0) sup[i][w] = bm;
  }
  __syncthreads();
  if (w == 0) {
    u64 kw0 = 0, kw1 = 0, kw2 = 0, kw3 = 0;   // finalized keep words
    #pragma unroll
    for (int c = 0; c < 5; ++c) {
      int i = c * 64 + lane;
      u64 srow[5];
      #pragma unroll
      for (int ww = 0; ww < 5; ++ww)
        srow[ww] = (ww <= c && i < MAXD) ? sup[i][ww] : 0ull;
      bool ext = ((srow[0] & kw0) | (srow[1] & kw1) | (srow[2] & kw2) | (srow[3] & kw3)) != 0ull;
      bool validme = (i < MAXD) && (validf[i] > 0.5f);
      u64 alive = __ballot(validme && !ext);
      unsigned mlo = (unsigned)srow[c], mhi = (unsigned)(srow[c] >> 32);
      for (int b = 0; b < 64; ++b) {
        if ((alive >> b) & 1ull) {
          u64 mi = ((u64)(unsigned)__shfl((int)mhi, b) << 32) | (u64)(unsigned)__shfl((int)mlo, b);
          if (b < 63) alive &= ~(mi & (~0ull << (b + 1)));
        }
      }
      if (c == 0) kw0 = alive;
      else if (c == 1) kw1 = alive;
      else if (c == 2) kw2 = alive;
      else if (c == 3) kw3 = alive;
      if (lane == 0) skw[c] = alive;
    }
  }
  __syncthreads();
  for (int jj = t; jj < MAXD; jj += 320)
    keepf[jj] = ((skw[jj >> 6] >> (jj & 63)) & 1ull) ? 1.f : 0.f;
}

// crop + 3x3 SAME conv(16) + ReLU + 2x2 maxpool -> feats[det][16384] (bf16)
__global__ __launch_bounds__(256) void k_cropconv(const float* __restrict__ image,
                                                  const float* __restrict__ Wc,
                                                  const float* __restrict__ bc,
                                                  const int* __restrict__ xy1,
                                                  short* __restrict__ feats) {
  __shared__ __align__(16) float crop[3][18][68];   // 14688 B, halo slice
  int det = blockIdx.x, sl = blockIdx.y, tid = threadIdx.x;
  int pr0 = sl * 8;                 // pooled rows pr0..pr0+7
  int gyBase = pr0 * 2 - 1;         // global crop row of local ry=0
  for (int i = tid; i < 3 * 18 * 68; i += 256) ((float*)crop)[i] = 0.f;
  __syncthreads();
  int x0 = xy1[det * 2 + 0], y0 = xy1[det * 2 + 1];
  for (int u = tid; u < 3 * 18 * 64; u += 256) {
    int c = u / 1152, rem = u % 1152, ry = rem >> 6, x = rem & 63;
    int gy = gyBase + ry;
    if (gy >= 0 && gy < CROPW)
      crop[c][ry][x + 1] = image[(size_t)c * (IMGW * IMGW) + (y0 + gy) * IMGW + x0 + x];
  }
  int ch = tid >> 4, px = tid & 15;
  float w[27];
  #pragma unroll
  for (int i = 0; i < 27; i++) w[i] = Wc[ch * 27 + i];
  float bias = bc[ch];
  __syncthreads();
  #pragma unroll
  for (int pr = 0; pr < 8; pr++) {
    float acc0[4] = {0.f, 0.f, 0.f, 0.f};
    float acc1[4] = {0.f, 0.f, 0.f, 0.f};
    #pragma unroll
    for (int c = 0; c < 3; c++) {
      #pragma unroll
      for (int r = 0; r < 4; r++) {
        const float* rp = &crop[c][2 * pr + r][4 * px];
        f32x4 a = *(const f32x4*)rp;          // 16B-aligned ds_read_b128
        float e0 = rp[4], e1 = rp[5];
        float in[6] = {a[0], a[1], a[2], a[3], e0, e1};
        if (r <= 2) {
          const float w0 = w[c * 9 + r * 3], w1 = w[c * 9 + r * 3 + 1], w2 = w[c * 9 + r * 3 + 2];
          #pragma unroll
          for (int q = 0; q < 4; q++)
            acc0[q] += in[q] * w0 + in[q + 1] * w1 + in[q + 2] * w2;
        }
        if (r >= 1) {
          const float w0 = w[c * 9 + (r - 1) * 3], w1 = w[c * 9 + (r - 1) * 3 + 1], w2 = w[c * 9 + (r - 1) * 3 + 2];
          #pragma unroll
          for (int q = 0; q < 4; q++)
            acc1[q] += in[q] * w0 + in[q + 1] * w1 + in[q + 2] * w2;
        }
      }
    }
    float m0 = fmaxf(fmaxf(acc0[0], acc0[1]), fmaxf(acc1[0], acc1[1]));
    float m1 = fmaxf(fmaxf(acc0[2], acc0[3]), fmaxf(acc1[2], acc1[3]));
    unsigned lo = f2bf(fmaxf(m0 + bias, 0.f));
    unsigned hi = f2bf(fmaxf(m1 + bias, 0.f));
    *(unsigned*)&feats[(size_t)det * 16384 + ch * 1024 + (pr0 + pr) * 32 + 2 * px] =
        lo | (hi << 16);
  }
}

// Fused FC1 GEMM: feats[320][16384] bf16 x W1[head][16384][128] f32 (direct)
// -> part f32 [ksplit][head][320][128].
// Grid (16 ks, 8 heads, 2 d-halves) = 256 blocks x 512 thr.
// Per block: M=320 (full), N=64, K=1024 -> every W1 byte read by ~1 block.
// A: LDS [320][64] bf16 double-buffered, 16B-chunk XOR swizzle (c^(m&7)).
// B: NO LDS -- fragments loaded directly from W1 as scalar dwords (lanes
//    cover 16 consecutive d = 64B segments), cvt f32->bf16 in regs; next
//    tile's B issued before current tile's MFMAs (latency hidden).
__global__ __launch_bounds__(512, 2) void k_gemm(const short* __restrict__ feats,
                                                 const float* __restrict__ W1,
                                                 float* __restrict__ part) {
  __shared__ __align__(16) short As[2][320 * 64];   // 81920 B
  int tid = threadIdx.x;
  int wid = tid >> 6, lane = tid & 63;
  int wm = wid & 3, wn = wid >> 2;          // 4 m-waves x 2 n-waves
  int lr = lane & 15, kg = lane >> 4;
  int ks = blockIdx.x, hd = blockIdx.y, dh = blockIdx.z;
  const int f0 = ks * 1024, d0 = dh * 64;
  const float* w1h = W1 + (size_t)hd * 16384 * 128;

  f32x4 acc[5][2];
  #pragma unroll
  for (int i = 0; i < 5; i++)
    #pragma unroll
    for (int j = 0; j < 2; j++) acc[i][j] = (f32x4){0.f, 0.f, 0.f, 0.f};

  // prologue: A tile 0 + B tile 0
  s16x8 aR[5];
  #pragma unroll
  for (int i = 0; i < 5; i++) {
    int ch = tid + i * 512, m = ch >> 3, c = ch & 7;
    aR[i] = *(const s16x8*)(feats + (size_t)m * 16384 + f0 + c * 8);
  }
  const float* bp = w1h + (size_t)(f0 + kg * 8) * 128 + d0 + wn * 32 + lr;
  float bF[2][2][8];
  #pragma unroll
  for (int k32 = 0; k32 < 2; k32++)
    #pragma unroll
    for (int nf = 0; nf < 2; nf++)
      #pragma unroll
      for (int j = 0; j < 8; j++)
        bF[k32][nf][j] = bp[(k32 * 32 + j) * 128 + nf * 16];
  #pragma unroll
  for (int i = 0; i < 5; i++) {
    int ch = tid + i * 512, m = ch >> 3, c = ch & 7;
    *(s16x8*)((char*)&As[0][0] + m * 128 + ((c ^ (m & 7)) << 4)) = aR[i];
  }
  __syncthreads();

  for (int t = 0; t < 16; ++t) {
    int cur = t & 1;
    // convert current B to bf16 frags (bF then free for prefetch)
    s16x8 bfr[2][2];
    #pragma unroll
    for (int k32 = 0; k32 < 2; k32++)
      #pragma unroll
      for (int nf = 0; nf < 2; nf++)
        #pragma unroll
        for (int j = 0; j < 8; j++)
          bfr[k32][nf][j] = (short)f2bf(bF[k32][nf][j]);
    bool pf = (t + 1) < 16;
    if (pf) {                                 // issue next-tile loads early
      int f1 = f0 + (t + 1) * 64;
      #pragma unroll
      for (int i = 0; i < 5; i++) {
        int ch = tid + i * 512, m = ch >> 3, c = ch & 7;
        aR[i] = *(const s16x8*)(feats + (size_t)m * 16384 + f1 + c * 8);
      }
      const float* bp2 = bp + (size_t)(t + 1) * 64 * 128;
      #pragma unroll
      for (int k32 = 0; k32 < 2; k32++)
        #pragma unroll
        for (int nf = 0; nf < 2; nf++)
          #pragma unroll
          for (int j = 0; j < 8; j++)
            bF[k32][nf][j] = bp2[(k32 * 32 + j) * 128 + nf * 16];
    }
    #pragma unroll
    for (int k32 = 0; k32 < 2; ++k32) {
      s16x8 af[5];
      #pragma unroll
      for (int mf = 0; mf < 5; ++mf) {
        int row = wm * 80 + mf * 16 + lr;
        int c = k32 * 4 + kg;
        af[mf] = *(const s16x8*)((const char*)&As[cur][0] + row * 128 + ((c ^ (row & 7)) << 4));
      }
      #pragma unroll
      for (int nf = 0; nf < 2; ++nf)
        #pragma unroll
        for (int mf = 0; mf < 5; ++mf)
          acc[mf][nf] = __builtin_amdgcn_mfma_f32_16x16x32_bf16(af[mf], bfr[k32][nf], acc[mf][nf], 0, 0, 0);
    }
    if (pf) {                                 // write next tile (other buffer)
      #pragma unroll
      for (int i = 0; i < 5; i++) {
        int ch = tid + i * 512, m = ch >> 3, c = ch & 7;
        *(s16x8*)((char*)&As[cur ^ 1][0] + m * 128 + ((c ^ (m & 7)) << 4)) = aR[i];
      }
      __syncthreads();
    }
  }
  #pragma unroll
  for (int mf = 0; mf < 5; ++mf)
    #pragma unroll
    for (int nf = 0; nf < 2; ++nf)
      #pragma unroll
      for (int r = 0; r < 4; ++r) {
        int m = wm * 80 + mf * 16 + kg * 4 + r;   // C/D: row=(lane>>4)*4+r, col=lane&15
        int d = d0 + wn * 32 + nf * 16 + lr;
        part[(((size_t)ks * 8 + hd) * 320 + m) * 128 + d] = acc[mf][nf][r];
      }
}

__global__ __launch_bounds__(256) void k_reduce(const float* __restrict__ part,
                                                const float* __restrict__ b1,
                                                float* __restrict__ h) {
  int o = blockIdx.x * 256 + threadIdx.x;    // 8*300*128 = 307200
  int d = o & 127;
  int k = (o >> 7) % 300;
  int hh = o / (128 * 300);
  float s = 0.f;
  #pragma unroll
  for (int ksp = 0; ksp < KSPLIT; ksp++)
    s += part[(((size_t)ksp * 8 + hh) * 320 + k) * 128 + d];
  s += b1[hh * 128 + d];
  h[o] = fmaxf(s, 0.f);
}

__global__ __launch_bounds__(320) void k_fc2(const float* __restrict__ h,
                                             const float* __restrict__ keepf,
                                             const float* __restrict__ W2p,
                                             const float* __restrict__ b2p,
                                             const float* __restrict__ W2a,
                                             const float* __restrict__ b2a,
                                             const float* __restrict__ W2d,
                                             const float* __restrict__ b2d,
                                             float* __restrict__ out) {
  int det = blockIdx.x, t = threadIdx.x;
  __shared__ float hl[1024];
  for (int i = t; i < 1024; i += 320) {
    int hh = i >> 7, d = i & 127;
    hl[i] = h[((size_t)hh * 300 + det) * 128 + d];
  }
  __syncthreads();
  if (t >= 273) return;
  float kf = keepf[det];
  float s = 0.f, bias;
  if (t < 38) {
    const float* hp = hl;                        // head 0
    for (int d = 0; d < 128; d++) s += hp[d] * W2p[d * 38 + t];
    bias = b2p[t];
  } else if (t < 63) {
    int c = t - 38;
    const float* hp = hl + 128;                  // head 1
    for (int d = 0; d < 128; d++) s += hp[d] * W2a[d * 25 + c];
    bias = b2a[c];
  } else {
    int u = t - 63, j = u / 35, o = u - j * 35;
    const float* hp = hl + (2 + j) * 128;        // heads 2..7
    for (int d = 0; d < 128; d++) s += hp[d] * W2d[((size_t)j * 128 + d) * 35 + o];
    bias = b2d[j * 35 + o];
  }
  out[det * 273 + t] = (s + bias) * kf;
}

extern "C" void kernel_launch(void* const* d_in, const int* in_sizes, int n_in,
                              void* d_out, int out_size, void* d_ws, size_t ws_size,
                              hipStream_t stream) {
  (void)in_sizes; (void)n_in; (void)out_size; (void)ws_size;
  const float* preds = (const float*)d_in[0];
  const float* image = (const float*)d_in[1];
  const float* Wc    = (const float*)d_in[2];
  const float* bc    = (const float*)d_in[3];
  const float* W1    = (const float*)d_in[4];
  const float* b1    = (const float*)d_in[5];
  const float* W2p   = (const float*)d_in[6];
  const float* b2p   = (const float*)d_in[7];
  const float* W2a   = (const float*)d_in[8];
  const float* b2a   = (const float*)d_in[9];
  const float* W2d   = (const float*)d_in[10];
  const float* b2d   = (const float*)d_in[11];

  char* ws = (char*)d_ws;
  unsigned* hist   = (unsigned*)(ws + OFF_HIST);
  unsigned* cnt    = (unsigned*)(ws + OFF_CNT);
  unsigned* cut    = (unsigned*)(ws + OFF_CUT);
  u64*      cand   = (u64*)(ws + OFF_CAND);
  float*    boxes  = (float*)(ws + OFF_BOXES);
  int*      xy1    = (int*)(ws + OFF_XY1);
  float*    validf = (float*)(ws + OFF_VALID);
  float*    keepf  = (float*)(ws + OFF_KEEP);
  float*    hbuf   = (float*)(ws + OFF_H);
  short*    feats  = (short*)(ws + OFF_FEATS);
  float*    part   = (float*)(ws + OFF_PART);
  float*    out    = (float*)d_out;

  hipMemsetAsync(ws, 0, CTRL_BYTES, stream);
  k_hist<<<(N_PRED + 255) / 256, 256, 0, stream>>>(preds, hist);
  k_findcut<<<1, 256, 0, stream>>>(hist, cut);
  k_compact<<<(N_PRED + 255) / 256, 256, 0, stream>>>(preds, cut, cnt, cand);
  k_sortprep<<<1, 1024, 0, stream>>>(preds, cand, boxes, xy1, validf);
  k_iou_nms<<<1, 320, 0, stream>>>(boxes, validf, keepf);
  k_cropconv<<<dim3(300, 4), 256, 0, stream>>>(image, Wc, bc, xy1, feats);
  k_gemm<<<dim3(KSPLIT, 8, 2), 512, 0, stream>>>(feats, W1, part);
  k_reduce<<<1200, 256, 0, stream>>>(part, b1, hbuf);
  k_fc2<<<MAXD, 320, 0, stream>>>(hbuf, keepf, W2p, b2p, W2a, b2a, W2d, b2d, out);
}

// Round 6
// 171.045 us; speedup vs baseline: 2.0369x; 1.0767x over previous
//
#include <hip/hip_runtime.h>

#define N_PRED 25200
#define CONF 0.25f
#define IOU_THR 0.45f
#define MAXD 300
#define IMGW 640
#define CROPW 64
#define HISTN 16640
#define KSPLIT 16

typedef float f32x4 __attribute__((ext_vector_type(4)));
typedef short s16x8 __attribute__((ext_vector_type(8)));
typedef unsigned long long u64;

// ---- workspace layout (bytes) ----
#define OFF_HIST   0u            // 16640*4 = 66560
#define OFF_CNT    66560u        // counters (cnt at +0)
#define OFF_CUT    66624u
#define OFF_CAND   66816u        // 1024 * 8 = 8192
#define CTRL_BYTES 75008u        // memset [0, CTRL_BYTES) each call
#define OFF_BOXES  75008u        // 300*4*4
#define OFF_XY1    79872u        // 300*2*4
#define OFF_VALID  82432u        // 300*4
#define OFF_KEEP   83712u        // 300*4
#define OFF_H      97024u        // 8*300*128*4 = 1228800
#define OFF_FEATS  1325824u      // 320*16384*2 = 10485760
#define OFF_PART   11811584u     // 16*8*320*128*4 = 26214400 (ends ~38MB)

__device__ inline unsigned short f2bf(float x) {
  unsigned u = __float_as_uint(x);
  u += 0x7FFFu + ((u >> 16) & 1u);   // round-to-nearest-even
  return (unsigned short)(u >> 16);
}

// ---------------- stage 1: score histogram (radix cut for top-300) -------
__global__ __launch_bounds__(256) void k_hist(const float* __restrict__ preds,
                                              unsigned* __restrict__ hist) {
  int i = blockIdx.x * 256 + threadIdx.x;
  if (i >= N_PRED) return;
  float s = preds[i * 6 + 4] * preds[i * 6 + 5];
  if (s > CONF) atomicAdd(&hist[__float_as_uint(s) >> 16], 1u);
}

// find largest bucket b with suffix-count(b) >= 300 (single scan pass)
__global__ __launch_bounds__(256) void k_findcut(const unsigned* __restrict__ hist,
                                                 unsigned* __restrict__ cut) {
  __shared__ unsigned s[256];
  int t = threadIdx.x;
  int base = t * 65;                       // 256*65 = 16640
  unsigned local = 0;
  for (int i = 0; i < 65; ++i) local += hist[base + i];
  s[t] = local;
  __syncthreads();
  for (int off = 1; off < 256; off <<= 1) {   // inclusive suffix scan
    unsigned add = (t + off < 256) ? s[t + off] : 0u;
    __syncthreads();
    s[t] += add;
    __syncthreads();
  }
  unsigned incl = s[t];
  unsigned excl = (t < 255) ? s[t + 1] : 0u;
  if (incl >= (unsigned)MAXD && excl < (unsigned)MAXD) {   // unique owning thread
    unsigned acc = excl, res = 0u;
    #pragma unroll
    for (int ii = 64; ii >= 0; --ii) {
      acc += hist[base + ii];
      if (res == 0u && acc >= (unsigned)MAXD) res = (unsigned)(base + ii);
    }
    cut[0] = res;
  }
}

__global__ __launch_bounds__(256) void k_compact(const float* __restrict__ preds,
                                                 const unsigned* __restrict__ cut,
                                                 unsigned* __restrict__ cnt,
                                                 u64* __restrict__ cand) {
  int i = blockIdx.x * 256 + threadIdx.x;
  if (i >= N_PRED) return;
  float s = preds[i * 6 + 4] * preds[i * 6 + 5];
  if (s <= CONF) return;
  unsigned bits = __float_as_uint(s);
  if ((bits >> 16) < cut[0]) return;
  unsigned pos = atomicAdd(cnt, 1u);
  if (pos < 1024u)
    cand[pos] = ((u64)bits << 32) | (u64)(0xFFFFFFFFu - (unsigned)i);  // ties: lower idx first
}

// bitonic sort 1024 u64 descending; emit boxes / crop coords / valid flags
__global__ __launch_bounds__(1024) void k_sortprep(const float* __restrict__ preds,
                                                   const u64* __restrict__ cand,
                                                   float* __restrict__ boxes,
                                                   int* __restrict__ xy1,
                                                   float* __restrict__ validf) {
  __shared__ u64 sk[1024];
  int t = threadIdx.x;
  sk[t] = cand[t];
  __syncthreads();
  for (int k = 2; k <= 1024; k <<= 1)
    for (int j = k >> 1; j > 0; j >>= 1) {
      int p = t ^ j;
      if (p > t) {
        u64 a = sk[t], b = sk[p];
        bool up = ((t & k) == 0);
        bool sw = up ? (a < b) : (a > b);      // descending overall
        if (sw) { sk[t] = b; sk[p] = a; }
      }
      __syncthreads();
    }
  if (t < MAXD) {
    u64 key = sk[t];
    if (key != 0ull) {
      int idx = (int)(0xFFFFFFFFu - (unsigned)(key & 0xFFFFFFFFull));
      float cx = preds[idx * 6 + 0], cy = preds[idx * 6 + 1];
      float w  = preds[idx * 6 + 2], h  = preds[idx * 6 + 3];
      float x1 = cx - w * 0.5f, y1 = cy - h * 0.5f;
      float x2 = cx + w * 0.5f, y2 = cy + h * 0.5f;
      boxes[t * 4 + 0] = x1; boxes[t * 4 + 1] = y1;
      boxes[t * 4 + 2] = x2; boxes[t * 4 + 3] = y2;
      int xi = (int)rintf(x1); xi = min(max(xi, 0), IMGW - CROPW);
      int yi = (int)rintf(y1); yi = min(max(yi, 0), IMGW - CROPW);
      xy1[t * 2 + 0] = xi; xy1[t * 2 + 1] = yi;
      validf[t] = 1.0f;
    } else {
      boxes[t * 4 + 0] = 0.f; boxes[t * 4 + 1] = 0.f;
      boxes[t * 4 + 2] = 0.f; boxes[t * 4 + 3] = 0.f;
      xy1[t * 2 + 0] = 0; xy1[t * 2 + 1] = 0;
      validf[t] = 0.f;
    }
  }
}

// fused IoU-matrix + greedy NMS: one block, 5 waves.
// Matrix build: unroll-4 so independent ds_read_b128+ballot groups pipeline.
// Greedy recurrence: fully-unrolled 64-bit chunks -> readlane (SALU chain),
// no bpermute on the critical path.
__global__ __launch_bounds__(320) void k_iou_nms(const float* __restrict__ boxes,
                                                 const float* __restrict__ validf,
                                                 float* __restrict__ keepf) {
  __shared__ __align__(16) float sb[MAXD][4];
  __shared__ u64 sup[MAXD][5];
  __shared__ u64 skw[5];
  int t = threadIdx.x;
  int w = t >> 6, lane = t & 63;
  for (int i = t; i < MAXD * 4; i += 320) ((float*)sb)[i] = boxes[i];
  __syncthreads();
  int j = t;                                 // my column (0..319)
  float bx1 = 0.f, by1 = 0.f, bx2 = 0.f, by2 = 0.f, arj = 0.f;
  if (j < MAXD) {
    bx1 = sb[j][0]; by1 = sb[j][1]; bx2 = sb[j][2]; by2 = sb[j][3];
    arj = (bx2 - bx1) * (by2 - by1);
  }
  #pragma unroll 4
  for (int i = 0; i < MAXD; ++i) {
    f32x4 bi = *(const f32x4*)&sb[i][0];
    float x1 = bi[0], y1 = bi[1], x2 = bi[2], y2 = bi[3];
    float ar = (x2 - x1) * (y2 - y1);
    float iw = fmaxf(fminf(x2, bx2) - fmaxf(x1, bx1), 0.f);
    float ih = fmaxf(fminf(y2, by2) - fmaxf(y1, by1), 0.f);
    float inter = iw * ih;
    float iou = inter / (ar + arj - inter + 1e-7f);
    u64 bm = __ballot((j < MAXD) && (iou > IOU_THR));
    if (lane == 0) sup[i][w] = bm;
  }
  __syncthreads();
  if (w == 0) {
    u64 kw0 = 0, kw1 = 0, kw2 = 0, kw3 = 0;   // finalized keep words
    #pragma unroll
    for (int c = 0; c < 5; ++c) {
      int i = c * 64 + lane;
      u64 srow[5];
      #pragma unroll
      for (int ww = 0; ww < 5; ++ww)
        srow[ww] = (ww <= c && i < MAXD) ? sup[i][ww] : 0ull;
      bool ext = ((srow[0] & kw0) | (srow[1] & kw1) | (srow[2] & kw2) | (srow[3] & kw3)) != 0ull;
      bool validme = (i < MAXD) && (validf[i] > 0.5f);
      u64 alive = __ballot(validme && !ext);
      unsigned mlo = (unsigned)srow[c], mhi = (unsigned)(srow[c] >> 32);
      #pragma unroll
      for (int b = 0; b < 64; ++b) {
        if ((alive >> b) & 1ull) {            // wave-uniform -> scalar branch
          u64 mi = ((u64)(unsigned)__builtin_amdgcn_readlane((int)mhi, b) << 32) |
                   (u64)(unsigned)__builtin_amdgcn_readlane((int)mlo, b);
          if (b < 63) alive &= ~(mi & (~0ull << (b + 1)));
        }
      }
      if (c == 0) kw0 = alive;
      else if (c == 1) kw1 = alive;
      else if (c == 2) kw2 = alive;
      else if (c == 3) kw3 = alive;
      if (lane == 0) skw[c] = alive;
    }
  }
  __syncthreads();
  for (int jj = t; jj < MAXD; jj += 320)
    keepf[jj] = ((skw[jj >> 6] >> (jj & 63)) & 1ull) ? 1.f : 0.f;
}

// crop + 3x3 SAME conv(16) + ReLU + 2x2 maxpool -> feats[det][16384] (bf16)
__global__ __launch_bounds__(256) void k_cropconv(const float* __restrict__ image,
                                                  const float* __restrict__ Wc,
                                                  const float* __restrict__ bc,
                                                  const int* __restrict__ xy1,
                                                  short* __restrict__ feats) {
  __shared__ __align__(16) float crop[3][18][68];   // 14688 B, halo slice
  int det = blockIdx.x, sl = blockIdx.y, tid = threadIdx.x;
  int pr0 = sl * 8;                 // pooled rows pr0..pr0+7
  int gyBase = pr0 * 2 - 1;         // global crop row of local ry=0
  for (int i = tid; i < 3 * 18 * 68; i += 256) ((float*)crop)[i] = 0.f;
  __syncthreads();
  int x0 = xy1[det * 2 + 0], y0 = xy1[det * 2 + 1];
  for (int u = tid; u < 3 * 18 * 64; u += 256) {
    int c = u / 1152, rem = u % 1152, ry = rem >> 6, x = rem & 63;
    int gy = gyBase + ry;
    if (gy >= 0 && gy < CROPW)
      crop[c][ry][x + 1] = image[(size_t)c * (IMGW * IMGW) + (y0 + gy) * IMGW + x0 + x];
  }
  int ch = tid >> 4, px = tid & 15;
  float w[27];
  #pragma unroll
  for (int i = 0; i < 27; i++) w[i] = Wc[ch * 27 + i];
  float bias = bc[ch];
  __syncthreads();
  #pragma unroll
  for (int pr = 0; pr < 8; pr++) {
    float acc0[4] = {0.f, 0.f, 0.f, 0.f};
    float acc1[4] = {0.f, 0.f, 0.f, 0.f};
    #pragma unroll
    for (int c = 0; c < 3; c++) {
      #pragma unroll
      for (int r = 0; r < 4; r++) {
        const float* rp = &crop[c][2 * pr + r][4 * px];
        f32x4 a = *(const f32x4*)rp;          // 16B-aligned ds_read_b128
        float e0 = rp[4], e1 = rp[5];
        float in[6] = {a[0], a[1], a[2], a[3], e0, e1};
        if (r <= 2) {
          const float w0 = w[c * 9 + r * 3], w1 = w[c * 9 + r * 3 + 1], w2 = w[c * 9 + r * 3 + 2];
          #pragma unroll
          for (int q = 0; q < 4; q++)
            acc0[q] += in[q] * w0 + in[q + 1] * w1 + in[q + 2] * w2;
        }
        if (r >= 1) {
          const float w0 = w[c * 9 + (r - 1) * 3], w1 = w[c * 9 + (r - 1) * 3 + 1], w2 = w[c * 9 + (r - 1) * 3 + 2];
          #pragma unroll
          for (int q = 0; q < 4; q++)
            acc1[q] += in[q] * w0 + in[q + 1] * w1 + in[q + 2] * w2;
        }
      }
    }
    float m0 = fmaxf(fmaxf(acc0[0], acc0[1]), fmaxf(acc1[0], acc1[1]));
    float m1 = fmaxf(fmaxf(acc0[2], acc0[3]), fmaxf(acc1[2], acc1[3]));
    unsigned lo = f2bf(fmaxf(m0 + bias, 0.f));
    unsigned hi = f2bf(fmaxf(m1 + bias, 0.f));
    *(unsigned*)&feats[(size_t)det * 16384 + ch * 1024 + (pr0 + pr) * 32 + 2 * px] =
        lo | (hi << 16);
  }
}

// Fused FC1 GEMM: feats[320][16384] bf16 x W1[head][16384][128] f32 (direct)
// -> part f32 [ksplit][head][320][128].
// Grid (16 ks, 8 heads, 2 d-halves) = 256 blocks x 512 thr.
// A: LDS [320][64] bf16 double-buffered, 16B-chunk XOR swizzle (c^(m&7)).
// B: direct-from-global scalar dwords, cvt f32->bf16 in regs, prefetched.
__global__ __launch_bounds__(512, 2) void k_gemm(const short* __restrict__ feats,
                                                 const float* __restrict__ W1,
                                                 float* __restrict__ part) {
  __shared__ __align__(16) short As[2][320 * 64];   // 81920 B
  int tid = threadIdx.x;
  int wid = tid >> 6, lane = tid & 63;
  int wm = wid & 3, wn = wid >> 2;          // 4 m-waves x 2 n-waves
  int lr = lane & 15, kg = lane >> 4;
  int ks = blockIdx.x, hd = blockIdx.y, dh = blockIdx.z;
  const int f0 = ks * 1024, d0 = dh * 64;
  const float* w1h = W1 + (size_t)hd * 16384 * 128;

  f32x4 acc[5][2];
  #pragma unroll
  for (int i = 0; i < 5; i++)
    #pragma unroll
    for (int j = 0; j < 2; j++) acc[i][j] = (f32x4){0.f, 0.f, 0.f, 0.f};

  // prologue: A tile 0 + B tile 0
  s16x8 aR[5];
  #pragma unroll
  for (int i = 0; i < 5; i++) {
    int ch = tid + i * 512, m = ch >> 3, c = ch & 7;
    aR[i] = *(const s16x8*)(feats + (size_t)m * 16384 + f0 + c * 8);
  }
  const float* bp = w1h + (size_t)(f0 + kg * 8) * 128 + d0 + wn * 32 + lr;
  float bF[2][2][8];
  #pragma unroll
  for (int k32 = 0; k32 < 2; k32++)
    #pragma unroll
    for (int nf = 0; nf < 2; nf++)
      #pragma unroll
      for (int j = 0; j < 8; j++)
        bF[k32][nf][j] = bp[(k32 * 32 + j) * 128 + nf * 16];
  #pragma unroll
  for (int i = 0; i < 5; i++) {
    int ch = tid + i * 512, m = ch >> 3, c = ch & 7;
    *(s16x8*)((char*)&As[0][0] + m * 128 + ((c ^ (m & 7)) << 4)) = aR[i];
  }
  __syncthreads();

  for (int t = 0; t < 16; ++t) {
    int cur = t & 1;
    s16x8 bfr[2][2];
    #pragma unroll
    for (int k32 = 0; k32 < 2; k32++)
      #pragma unroll
      for (int nf = 0; nf < 2; nf++)
        #pragma unroll
        for (int j = 0; j < 8; j++)
          bfr[k32][nf][j] = (short)f2bf(bF[k32][nf][j]);
    bool pf = (t + 1) < 16;
    if (pf) {                                 // issue next-tile loads early
      int f1 = f0 + (t + 1) * 64;
      #pragma unroll
      for (int i = 0; i < 5; i++) {
        int ch = tid + i * 512, m = ch >> 3, c = ch & 7;
        aR[i] = *(const s16x8*)(feats + (size_t)m * 16384 + f1 + c * 8);
      }
      const float* bp2 = bp + (size_t)(t + 1) * 64 * 128;
      #pragma unroll
      for (int k32 = 0; k32 < 2; k32++)
        #pragma unroll
        for (int nf = 0; nf < 2; nf++)
          #pragma unroll
          for (int j = 0; j < 8; j++)
            bF[k32][nf][j] = bp2[(k32 * 32 + j) * 128 + nf * 16];
    }
    #pragma unroll
    for (int k32 = 0; k32 < 2; ++k32) {
      s16x8 af[5];
      #pragma unroll
      for (int mf = 0; mf < 5; ++mf) {
        int row = wm * 80 + mf * 16 + lr;
        int c = k32 * 4 + kg;
        af[mf] = *(const s16x8*)((const char*)&As[cur][0] + row * 128 + ((c ^ (row & 7)) << 4));
      }
      #pragma unroll
      for (int nf = 0; nf < 2; ++nf)
        #pragma unroll
        for (int mf = 0; mf < 5; ++mf)
          acc[mf][nf] = __builtin_amdgcn_mfma_f32_16x16x32_bf16(af[mf], bfr[k32][nf], acc[mf][nf], 0, 0, 0);
    }
    if (pf) {                                 // write next tile (other buffer)
      #pragma unroll
      for (int i = 0; i < 5; i++) {
        int ch = tid + i * 512, m = ch >> 3, c = ch & 7;
        *(s16x8*)((char*)&As[cur ^ 1][0] + m * 128 + ((c ^ (m & 7)) << 4)) = aR[i];
      }
      __syncthreads();
    }
  }
  #pragma unroll
  for (int mf = 0; mf < 5; ++mf)
    #pragma unroll
    for (int nf = 0; nf < 2; ++nf)
      #pragma unroll
      for (int r = 0; r < 4; ++r) {
        int m = wm * 80 + mf * 16 + kg * 4 + r;   // C/D: row=(lane>>4)*4+r, col=lane&15
        int d = d0 + wn * 32 + nf * 16 + lr;
        part[(((size_t)ks * 8 + hd) * 320 + m) * 128 + d] = acc[mf][nf][r];
      }
}

__global__ __launch_bounds__(256) void k_reduce(const float* __restrict__ part,
                                                const float* __restrict__ b1,
                                                float* __restrict__ h) {
  int o = blockIdx.x * 256 + threadIdx.x;    // 8*300*128 = 307200
  int d = o & 127;
  int k = (o >> 7) % 300;
  int hh = o / (128 * 300);
  float s = 0.f;
  #pragma unroll
  for (int ksp = 0; ksp < KSPLIT; ksp++)
    s += part[(((size_t)ksp * 8 + hh) * 320 + k) * 128 + d];
  s += b1[hh * 128 + d];
  h[o] = fmaxf(s, 0.f);
}

__global__ __launch_bounds__(320) void k_fc2(const float* __restrict__ h,
                                             const float* __restrict__ keepf,
                                             const float* __restrict__ W2p,
                                             const float* __restrict__ b2p,
                                             const float* __restrict__ W2a,
                                             const float* __restrict__ b2a,
                                             const float* __restrict__ W2d,
                                             const float* __restrict__ b2d,
                                             float* __restrict__ out) {
  int det = blockIdx.x, t = threadIdx.x;
  __shared__ float hl[1024];
  for (int i = t; i < 1024; i += 320) {
    int hh = i >> 7, d = i & 127;
    hl[i] = h[((size_t)hh * 300 + det) * 128 + d];
  }
  __syncthreads();
  if (t >= 273) return;
  float kf = keepf[det];
  float s = 0.f, bias;
  if (t < 38) {
    const float* hp = hl;                        // head 0
    for (int d = 0; d < 128; d++) s += hp[d] * W2p[d * 38 + t];
    bias = b2p[t];
  } else if (t < 63) {
    int c = t - 38;
    const float* hp = hl + 128;                  // head 1
    for (int d = 0; d < 128; d++) s += hp[d] * W2a[d * 25 + c];
    bias = b2a[c];
  } else {
    int u = t - 63, j = u / 35, o = u - j * 35;
    const float* hp = hl + (2 + j) * 128;        // heads 2..7
    for (int d = 0; d < 128; d++) s += hp[d] * W2d[((size_t)j * 128 + d) * 35 + o];
    bias = b2d[j * 35 + o];
  }
  out[det * 273 + t] = (s + bias) * kf;
}

extern "C" void kernel_launch(void* const* d_in, const int* in_sizes, int n_in,
                              void* d_out, int out_size, void* d_ws, size_t ws_size,
                              hipStream_t stream) {
  (void)in_sizes; (void)n_in; (void)out_size; (void)ws_size;
  const float* preds = (const float*)d_in[0];
  const float* image = (const float*)d_in[1];
  const float* Wc    = (const float*)d_in[2];
  const float* bc    = (const float*)d_in[3];
  const float* W1    = (const float*)d_in[4];
  const float* b1    = (const float*)d_in[5];
  const float* W2p   = (const float*)d_in[6];
  const float* b2p   = (const float*)d_in[7];
  const float* W2a   = (const float*)d_in[8];
  const float* b2a   = (const float*)d_in[9];
  const float* W2d   = (const float*)d_in[10];
  const float* b2d   = (const float*)d_in[11];

  char* ws = (char*)d_ws;
  unsigned* hist   = (unsigned*)(ws + OFF_HIST);
  unsigned* cnt    = (unsigned*)(ws + OFF_CNT);
  unsigned* cut    = (unsigned*)(ws + OFF_CUT);
  u64*      cand   = (u64*)(ws + OFF_CAND);
  float*    boxes  = (float*)(ws + OFF_BOXES);
  int*      xy1    = (int*)(ws + OFF_XY1);
  float*    validf = (float*)(ws + OFF_VALID);
  float*    keepf  = (float*)(ws + OFF_KEEP);
  float*    hbuf   = (float*)(ws + OFF_H);
  short*    feats  = (short*)(ws + OFF_FEATS);
  float*    part   = (float*)(ws + OFF_PART);
  float*    out    = (float*)d_out;

  hipMemsetAsync(ws, 0, CTRL_BYTES, stream);
  k_hist<<<(N_PRED + 255) / 256, 256, 0, stream>>>(preds, hist);
  k_findcut<<<1, 256, 0, stream>>>(hist, cut);
  k_compact<<<(N_PRED + 255) / 256, 256, 0, stream>>>(preds, cut, cnt, cand);
  k_sortprep<<<1, 1024, 0, stream>>>(preds, cand, boxes, xy1, validf);
  k_iou_nms<<<1, 320, 0, stream>>>(boxes, validf, keepf);
  k_cropconv<<<dim3(300, 4), 256, 0, stream>>>(image, Wc, bc, xy1, feats);
  k_gemm<<<dim3(KSPLIT, 8, 2), 512, 0, stream>>>(feats, W1, part);
  k_reduce<<<1200, 256, 0, stream>>>(part, b1, hbuf);
  k_fc2<<<MAXD, 320, 0, stream>>>(hbuf, keepf, W2p, b2p, W2a, b2a, W2d, b2d, out);
}